// Round 5
// baseline (1012.111 us; speedup 1.0000x reference)
//
#include <hip/hip_runtime.h>
#include <hip/hip_bf16.h>

#define NN 100000
#define EE 400000
#define GG 4096
#define DD 128
#define ATOM_DIM 101
#define BOND_DIM 11
#define EAP 12   // padded bond-feature stride (48B, 16B-aligned)
#define NBLK 512 // persistent GEMM grid

typedef __attribute__((ext_vector_type(8))) short bf16x8;
typedef __attribute__((ext_vector_type(4))) float f32x4;
typedef __attribute__((ext_vector_type(2))) float f32x2;
typedef __attribute__((ext_vector_type(4))) short short4v;

__device__ __forceinline__ float b2f(short s) {
    unsigned u = ((unsigned)(unsigned short)s) << 16;
    float f; __builtin_memcpy(&f, &u, 4); return f;
}
__device__ __forceinline__ unsigned short f2b(float f) {
    unsigned u; __builtin_memcpy(&u, &f, 4);
    u += 0x7FFFu + ((u >> 16) & 1u);          // RNE
    return (unsigned short)(u >> 16);
}

// ---------------- index dtype detection (int32 vs int64) ----------------
__global__ void detect64_kernel(const void* ei, int npairs, int* flag) {
    const int* p = (const int*)ei;
    int any = 0;
    for (int i = 1; i < 2 * npairs; i += 2) any |= p[i];
    *flag = (any == 0) ? 1 : 0;
}
__device__ __forceinline__ int getIdx(const void* p, long i, int is64) {
    if (is64) return (int)(((const long long*)p)[i]);
    return ((const int*)p)[i];
}

// ---------------- counting sort by dst ----------------
__global__ __launch_bounds__(256) void hist_kernel(
    const void* __restrict__ eidx, const int* __restrict__ flag, int* __restrict__ counts) {
    int e = blockIdx.x * 256 + threadIdx.x;
    if (e >= EE) return;
    int is64 = *flag;
    int dn = getIdx(eidx, (long)EE + e, is64);
    atomicAdd(&counts[dn], 1);
}

__global__ __launch_bounds__(256) void scan1_kernel(
    const int* __restrict__ counts, int* __restrict__ tmp, int* __restrict__ bsum, int n) {
    __shared__ int sd[256];
    const int tid = threadIdx.x;
    int i = blockIdx.x * 256 + tid;
    int v = (i < n) ? counts[i] : 0;
    sd[tid] = v; __syncthreads();
    #pragma unroll
    for (int off = 1; off < 256; off <<= 1) {
        int a = (tid >= off) ? sd[tid - off] : 0;
        __syncthreads();
        sd[tid] += a;
        __syncthreads();
    }
    if (i < n) tmp[i] = sd[tid] - v;          // exclusive
    if (tid == 255) bsum[blockIdx.x] = sd[255];
}

__global__ __launch_bounds__(512) void scan2_kernel(
    const int* __restrict__ bsum, int* __restrict__ bsumx, int nb) {
    __shared__ int sd[512];
    const int tid = threadIdx.x;
    int v = (tid < nb) ? bsum[tid] : 0;
    sd[tid] = v; __syncthreads();
    #pragma unroll
    for (int off = 1; off < 512; off <<= 1) {
        int a = (tid >= off) ? sd[tid - off] : 0;
        __syncthreads();
        sd[tid] += a;
        __syncthreads();
    }
    if (tid < nb) bsumx[tid] = sd[tid] - v;   // exclusive
}

__global__ __launch_bounds__(256) void scan3_kernel(
    const int* __restrict__ tmp, const int* __restrict__ bsumx,
    int* __restrict__ row_ptr, int n) {
    int i = blockIdx.x * 256 + threadIdx.x;
    if (i < n) row_ptr[i] = tmp[i] + bsumx[blockIdx.x];
    if (i == 0) row_ptr[n] = EE;
}

__global__ __launch_bounds__(256) void scatter_kernel(
    const void* __restrict__ eidx, const int* __restrict__ flag,
    const float* __restrict__ ea, const int* __restrict__ row_ptr,
    int* __restrict__ cursor, int* __restrict__ src_sorted, float* __restrict__ eas) {
    int e = blockIdx.x * 256 + threadIdx.x;
    if (e >= EE) return;
    int is64 = *flag;
    int dn = getIdx(eidx, (long)EE + e, is64);
    int sv = getIdx(eidx, e, is64);
    int pos = row_ptr[dn] + atomicAdd(&cursor[dn], 1);
    src_sorted[pos] = sv;
    const float* sp = ea + (long)e * BOND_DIM;
    float* dp = eas + (long)pos * EAP;
    #pragma unroll
    for (int k = 0; k < BOND_DIM; ++k) dp[k] = sp[k];
    dp[11] = 0.f;
}

// ---------------- fused message + aggregate (CSR, no atomics) ----------------
// s[n] = t[n] + sum_{e in N(n)} relu(t[src[e]] + ea[e] @ bw + bb)
__global__ __launch_bounds__(256) void msg_csr_kernel(
    const unsigned short* __restrict__ t,
    const int* __restrict__ src_sorted, const int* __restrict__ row_ptr,
    const float* __restrict__ eas,
    const float* __restrict__ bw,   // [11][128]
    const float* __restrict__ bb,   // [128]
    float* __restrict__ sout)
{
    const int tid = threadIdx.x;
    const int wave = tid >> 6, lane = tid & 63;
    const int d0 = lane * 2;
    float wk0[BOND_DIM], wk1[BOND_DIM];
    #pragma unroll
    for (int k = 0; k < BOND_DIM; ++k) {
        f32x2 wv = *(const f32x2*)(bw + k * DD + d0);
        wk0[k] = wv.x; wk1[k] = wv.y;
    }
    f32x2 bbv = *(const f32x2*)(bb + d0);

    for (int n = blockIdx.x * 4 + wave; n < NN; n += gridDim.x * 4) {
        const int e0 = row_ptr[n], e1 = row_ptr[n + 1];
        float a0 = 0.f, a1 = 0.f;
        int e = e0;
        for (; e + 2 <= e1; e += 2) {
            int sv0 = src_sorted[e];
            int sv1 = src_sorted[e + 1];
            unsigned tva = *(const unsigned*)(t + (long)sv0 * DD + d0);
            unsigned tvb = *(const unsigned*)(t + (long)sv1 * DD + d0);
            const float* epa = eas + (long)e * EAP;
            const float* epb = epa + EAP;
            f32x4 a0v = *(const f32x4*)epa, a1v = *(const f32x4*)(epa + 4), a2v = *(const f32x4*)(epa + 8);
            f32x4 b0v = *(const f32x4*)epb, b1v = *(const f32x4*)(epb + 4), b2v = *(const f32x4*)(epb + 8);
            float eva[12] = {a0v.x, a0v.y, a0v.z, a0v.w, a1v.x, a1v.y, a1v.z, a1v.w, a2v.x, a2v.y, a2v.z, a2v.w};
            float evb[12] = {b0v.x, b0v.y, b0v.z, b0v.w, b1v.x, b1v.y, b1v.z, b1v.w, b2v.x, b2v.y, b2v.z, b2v.w};
            float ca0 = bbv.x, ca1 = bbv.y, cb0 = bbv.x, cb1 = bbv.y;
            #pragma unroll
            for (int k = 0; k < BOND_DIM; ++k) {
                ca0 = fmaf(eva[k], wk0[k], ca0);
                ca1 = fmaf(eva[k], wk1[k], ca1);
                cb0 = fmaf(evb[k], wk0[k], cb0);
                cb1 = fmaf(evb[k], wk1[k], cb1);
            }
            a0 += fmaxf(b2f((short)(tva & 0xffff)) + ca0, 0.f);
            a1 += fmaxf(b2f((short)(tva >> 16)) + ca1, 0.f);
            a0 += fmaxf(b2f((short)(tvb & 0xffff)) + cb0, 0.f);
            a1 += fmaxf(b2f((short)(tvb >> 16)) + cb1, 0.f);
        }
        if (e < e1) {
            int sv = src_sorted[e];
            unsigned tv = *(const unsigned*)(t + (long)sv * DD + d0);
            const float* ep = eas + (long)e * EAP;
            f32x4 ev0 = *(const f32x4*)ep, ev1 = *(const f32x4*)(ep + 4), ev2 = *(const f32x4*)(ep + 8);
            float ev[12] = {ev0.x, ev0.y, ev0.z, ev0.w, ev1.x, ev1.y, ev1.z, ev1.w, ev2.x, ev2.y, ev2.z, ev2.w};
            float c0 = bbv.x, c1 = bbv.y;
            #pragma unroll
            for (int k = 0; k < BOND_DIM; ++k) {
                c0 = fmaf(ev[k], wk0[k], c0);
                c1 = fmaf(ev[k], wk1[k], c1);
            }
            a0 += fmaxf(b2f((short)(tv & 0xffff)) + c0, 0.f);
            a1 += fmaxf(b2f((short)(tv >> 16)) + c1, 0.f);
        }
        unsigned tn = *(const unsigned*)(t + (long)n * DD + d0);
        f32x2 o;
        o.x = b2f((short)(tn & 0xffff)) + a0;
        o.y = b2f((short)(tn >> 16)) + a1;
        *(f32x2*)(sout + (long)n * DD + d0) = o;
    }
}

// ---------------- weight pre-pack: W[K][N] f32 -> Wf[ks][f][lane][8] bf16 ----
__global__ void pack_w(const float* __restrict__ W, unsigned short* __restrict__ Wf,
                       int Kact, int N, int KSTEPS) {
    int idx = blockIdx.x * blockDim.x + threadIdx.x;
    int NF = N >> 4;
    int total = KSTEPS * NF * 64;
    if (idx >= total) return;
    int l = idx & 63;
    int f = (idx >> 6) % NF;
    int ks = idx / (64 * NF);
    int col = f * 16 + (l & 15);
    int k0 = ks * 32 + (l >> 4) * 8;
    bf16x8 v;
    #pragma unroll
    for (int j = 0; j < 8; ++j) {
        int k = k0 + j;
        v[j] = (k < Kact) ? (short)f2b(W[(long)k * N + col]) : (short)0;
    }
    *(bf16x8*)(Wf + (long)idx * 8) = v;
}

// ---------------- x f32 [N,101] -> xb bf16 [N,128] zero-padded ----------------
__global__ void pack_x(const float* __restrict__ x, unsigned short* __restrict__ xb) {
    const long total = (long)NN * 128;
    for (long i = (long)blockIdx.x * blockDim.x + threadIdx.x; i < total;
         i += (long)gridDim.x * blockDim.x) {
        int col = (int)(i & 127);
        long row = i >> 7;
        xb[i] = (col < ATOM_DIM) ? f2b(x[row * ATOM_DIM + col]) : (unsigned short)0;
    }
}

// ---------------- t = bf16(relu(h*sc+sh)) ----------------
__global__ __launch_bounds__(256) void transform_kernel(
    const float* __restrict__ h, const float* __restrict__ sc,
    const float* __restrict__ sh, unsigned short* __restrict__ t) {
    long i = (long)blockIdx.x * blockDim.x + threadIdx.x;
    long base = i * 4;
    if (base >= (long)NN * DD) return;
    int col = (int)(base & 127);
    f32x4 hv = *(const f32x4*)(h + base);
    f32x4 s = *(const f32x4*)(sc + col);
    f32x4 b = *(const f32x4*)(sh + col);
    short4v o;
    o[0] = (short)f2b(fmaxf(hv.x * s.x + b.x, 0.f));
    o[1] = (short)f2b(fmaxf(hv.y * s.y + b.y, 0.f));
    o[2] = (short)f2b(fmaxf(hv.z * s.z + b.z, 0.f));
    o[3] = (short)f2b(fmaxf(hv.w * s.w + b.w, 0.f));
    *(short4v*)(t + base) = o;
}

// ---------------- persistent MFMA GEMM: B resident in LDS, reg stats ----------------
// MODE 0: A bf16.  MODE 2: bf16 relu(A*sc+sh).  MODE 3: A f32.
template<int NF, int KSTEPS, int MODE, bool OUT_BF16, bool STATS>
__global__ __launch_bounds__(256, 2) void gemm_mfma(
    const void* __restrict__ Ap,
    const float* __restrict__ sc, const float* __restrict__ sh,
    const unsigned short* __restrict__ Wf,  // packed [KSTEPS][NF][64][8]
    const float* __restrict__ bias,         // [NF*16]
    void* __restrict__ outp,
    float* __restrict__ partial,            // [NBLK][2*NC] per-block stats
    int M)
{
    constexpr int K = KSTEPS * 32;
    constexpr int NC = NF * 16;
    constexpr int UNITS = KSTEPS * NF * 64;       // 16B units (<=4096 -> 64KB)
    constexpr int SLOADS = UNITS / 256;

    __shared__ __align__(16) unsigned short sB[UNITS * 8];
    __shared__ float s_sum[NC];
    __shared__ float s_sq[NC];

    const int tid = threadIdx.x;
    const int wave = tid >> 6, l = tid & 63;
    const int kg = (l >> 4) * 8;
    const bf16x8* gW = (const bf16x8*)Wf;
    bf16x8* sB8 = (bf16x8*)sB;

    // stage entire B panel once
    {
        bf16x8 stg[SLOADS];
        #pragma unroll
        for (int i = 0; i < SLOADS; ++i) stg[i] = gW[i * 256 + tid];
        if (STATS) {
            for (int i = tid; i < NC; i += 256) { s_sum[i] = 0.f; s_sq[i] = 0.f; }
        }
        #pragma unroll
        for (int i = 0; i < SLOADS; ++i) sB8[i * 256 + tid] = stg[i];
    }
    __syncthreads();

    float ssum[NF], ssq[NF];
    #pragma unroll
    for (int f = 0; f < NF; ++f) { ssum[f] = 0.f; ssq[f] = 0.f; }

    const int ntiles = (M + 63) >> 6;
    for (int tile = blockIdx.x; tile < ntiles; tile += NBLK) {
        const int r0 = tile * 64 + wave * 16;
        const int rr = r0 + (l & 15);
        const int rc = rr < M ? rr : M - 1;

        bf16x8 af[KSTEPS];
        #pragma unroll
        for (int ks = 0; ks < KSTEPS; ++ks) {
            bf16x8 a;
            if (MODE == 3) {
                const float* ap = (const float*)Ap + (long)rc * K + ks * 32 + kg;
                f32x4 v0 = *(const f32x4*)ap, v1 = *(const f32x4*)(ap + 4);
                float vv[8] = {v0.x, v0.y, v0.z, v0.w, v1.x, v1.y, v1.z, v1.w};
                #pragma unroll
                for (int j = 0; j < 8; ++j) a[j] = (short)f2b(vv[j]);
            } else {
                const unsigned short* ap = (const unsigned short*)Ap + (long)rc * K + ks * 32 + kg;
                a = *(const bf16x8*)ap;
                if (MODE == 2) {
                    const float* scp = sc + ks * 32 + kg;
                    const float* shp = sh + ks * 32 + kg;
                    f32x4 s0 = *(const f32x4*)scp, s1 = *(const f32x4*)(scp + 4);
                    f32x4 h0 = *(const f32x4*)shp, h1 = *(const f32x4*)(shp + 4);
                    float sv[8] = {s0.x, s0.y, s0.z, s0.w, s1.x, s1.y, s1.z, s1.w};
                    float hv[8] = {h0.x, h0.y, h0.z, h0.w, h1.x, h1.y, h1.z, h1.w};
                    #pragma unroll
                    for (int j = 0; j < 8; ++j) {
                        float v = fmaxf(b2f(a[j]) * sv[j] + hv[j], 0.f);
                        a[j] = (short)f2b(v);
                    }
                }
            }
            af[ks] = a;
        }

        f32x4 acc[NF];
        #pragma unroll
        for (int f = 0; f < NF; ++f) acc[f] = (f32x4){0.f, 0.f, 0.f, 0.f};

        #pragma unroll
        for (int ks = 0; ks < KSTEPS; ++ks) {
            #pragma unroll
            for (int f = 0; f < NF; ++f) {
                bf16x8 b = sB8[(ks * NF + f) * 64 + l];
                acc[f] = __builtin_amdgcn_mfma_f32_16x16x32_bf16(af[ks], b, acc[f], 0, 0, 0);
            }
        }

        #pragma unroll
        for (int f = 0; f < NF; ++f) {
            const int col = f * 16 + (l & 15);
            const float bb = bias[col];
            #pragma unroll
            for (int j = 0; j < 4; ++j) {
                int r = r0 + (l >> 4) * 4 + j;
                if (r < M) {
                    float v = acc[f][j] + bb;
                    if (OUT_BF16) ((unsigned short*)outp)[(long)r * NC + col] = f2b(v);
                    else          ((float*)outp)[(long)r * NC + col] = v;
                    if (STATS) { ssum[f] += v; ssq[f] += v * v; }
                }
            }
        }
    }

    if (STATS) {
        #pragma unroll
        for (int f = 0; f < NF; ++f) {
            float s = ssum[f], q = ssq[f];
            s += __shfl_xor(s, 16); s += __shfl_xor(s, 32);
            q += __shfl_xor(q, 16); q += __shfl_xor(q, 32);
            if (l < 16) {
                atomicAdd(&s_sum[f * 16 + l], s);
                atomicAdd(&s_sq[f * 16 + l], q);
            }
        }
        __syncthreads();
        float* pb = partial + (long)blockIdx.x * 2 * NC;
        for (int i = tid; i < NC; i += 256) {
            pb[i] = s_sum[i];
            pb[NC + i] = s_sq[i];
        }
    }
}

// ---------------- BN finalize: sum per-block partials (C blocks x 64 lanes) ----------------
__global__ __launch_bounds__(64) void bn_finalize_p(
    const float* __restrict__ partial, int nblk, int C,
    const float* __restrict__ gamma, const float* __restrict__ beta,
    float invN, float* __restrict__ sc, float* __restrict__ sh)
{
    const int c = blockIdx.x;
    const int t = threadIdx.x;
    float s = 0.f, q = 0.f;
    for (int b = t; b < nblk; b += 64) {
        const float* pb = partial + (long)b * 2 * C;
        s += pb[c];
        q += pb[C + c];
    }
    #pragma unroll
    for (int off = 1; off < 64; off <<= 1) {
        s += __shfl_xor(s, off);
        q += __shfl_xor(q, off);
    }
    if (t == 0) {
        float m = s * invN;
        float v = q * invN - m * m;
        float g = gamma[c] * rsqrtf(v + 1e-5f);
        sc[c] = g;
        sh[c] = beta[c] - m * g;
    }
}

// ---------------- pooling ----------------
__global__ __launch_bounds__(128) void pool_kernel(
    const float* __restrict__ hraw,
    const float* __restrict__ sc, const float* __restrict__ sh,
    const void* __restrict__ batchp, const int* __restrict__ flag,
    int Nn, float* __restrict__ out)
{
    const int g = blockIdx.x;
    const int t = threadIdx.x;
    const int is64 = *flag;
    int lo = 0, hi = Nn;
    while (lo < hi) { int mid = (lo + hi) >> 1; if (getIdx(batchp, mid, is64) < g) lo = mid + 1; else hi = mid; }
    const int s0 = lo;
    hi = Nn;
    while (lo < hi) { int mid = (lo + hi) >> 1; if (getIdx(batchp, mid, is64) < g + 1) lo = mid + 1; else hi = mid; }
    const int s1 = lo;
    float acc = 0.f;
    for (int r = s0; r < s1; ++r) acc += hraw[(long)r * DD + t];
    const int cnt = s1 - s0;
    float v = 0.f;
    if (cnt > 0) v = (acc / (float)cnt) * sc[t] + sh[t];
    out[(long)g * DD + t] = v;
}

// ---------------- launch ----------------
extern "C" void kernel_launch(void* const* d_in, const int* in_sizes, int n_in,
                              void* d_out, int out_size, void* d_ws, size_t ws_size,
                              hipStream_t stream)
{
    const float* x     = (const float*)d_in[0];
    const float* ea    = (const float*)d_in[1];
    const float* embW  = (const float*)d_in[2];
    const float* embB  = (const float*)d_in[3];
    const float* bondW = (const float*)d_in[4];
    const float* bondB = (const float*)d_in[5];
    const float* W1    = (const float*)d_in[6];
    const float* b1    = (const float*)d_in[7];
    const float* g1    = (const float*)d_in[8];
    const float* be1   = (const float*)d_in[9];
    const float* W2    = (const float*)d_in[10];
    const float* b2    = (const float*)d_in[11];
    const float* gout  = (const float*)d_in[12];
    const float* bout  = (const float*)d_in[13];
    const void*  eidx  = d_in[14];
    const void*  batch = d_in[15];
    float* out = (float*)d_out;

    char* w = (char*)d_ws;
    unsigned short* t   = (unsigned short*)w;   w += (long)NN * DD * 2;        // 25.6MB
    unsigned short* z1  = (unsigned short*)w;   w += (long)NN * 256 * 2;       // 51.2MB
    unsigned short* xb  = z1;   // alias: consumed by emb gemm before z1 written
    float* h    = (float*)w;                    w += (long)NN * DD * 4;        // 51.2MB
    float* s    = h;            // alias: s consumed by gemm1 before gemm2 writes h
    float* eas  = (float*)w;                    w += (long)EE * EAP * 4;       // 19.2MB
    int* src_sorted = (int*)w;                  w += (long)EE * 4;             // 1.6MB
    int* row_ptr    = (int*)w;                  w += (long)(NN + 1) * 4;
    int* counts     = (int*)w;                  w += (long)NN * 4;
    int* tmp        = (int*)w;                  w += (long)NN * 4;
    int* bsum       = (int*)w;                  w += 1024 * 4;
    int* bsumx      = (int*)w;                  w += 1024 * 4;
    float* pz1  = (float*)w;                    w += (long)NBLK * 512 * 4;     // 1MB
    float* ph   = (float*)w;                    w += (long)NBLK * 256 * 4;     // 0.5MB
    float* sc1  = (float*)w;                    w += 256 * 4;
    float* sh1  = (float*)w;                    w += 256 * 4;
    float* sc2  = (float*)w;                    w += 128 * 4;
    float* sh2  = (float*)w;                    w += 128 * 4;
    unsigned short* embWf = (unsigned short*)w; w += 4 * 8  * 64 * 8 * 2;
    unsigned short* W1f   = (unsigned short*)w; w += 3L * 4 * 16 * 64 * 8 * 2;
    unsigned short* W2f   = (unsigned short*)w; w += 3L * 8 * 8  * 64 * 8 * 2;
    int* flag = (int*)w;

    detect64_kernel<<<1, 1, 0, stream>>>(eidx, 256, flag);

    // pre-pack weights / x
    pack_x<<<4096, 256, 0, stream>>>(x, xb);
    pack_w<<<8, 256, 0, stream>>>(embW, embWf, ATOM_DIM, 128, 4);
    for (int i = 0; i < 3; ++i) {
        pack_w<<<16, 256, 0, stream>>>(W1 + (long)i * 128 * 256, W1f + (long)i * 4 * 16 * 64 * 8, 128, 256, 4);
        pack_w<<<16, 256, 0, stream>>>(W2 + (long)i * 256 * 128, W2f + (long)i * 8 * 8 * 64 * 8, 256, 128, 8);
    }

    // counting sort of edges by dst -> CSR
    const int eblocks = (EE + 255) / 256;
    const int nb = (NN + 255) / 256;   // 391
    hipMemsetAsync(counts, 0, (size_t)NN * 4, stream);
    hist_kernel<<<eblocks, 256, 0, stream>>>(eidx, flag, counts);
    scan1_kernel<<<nb, 256, 0, stream>>>(counts, tmp, bsum, NN);
    scan2_kernel<<<1, 512, 0, stream>>>(bsum, bsumx, nb);
    scan3_kernel<<<nb, 256, 0, stream>>>(tmp, bsumx, row_ptr, NN);
    hipMemsetAsync(counts, 0, (size_t)NN * 4, stream);
    scatter_kernel<<<eblocks, 256, 0, stream>>>(eidx, flag, ea, row_ptr, counts, src_sorted, eas);

    // t = bf16(x @ embW + embB)
    gemm_mfma<8, 4, 0, true, false><<<NBLK, 256, 0, stream>>>(
        xb, nullptr, nullptr, embWf, embB, t, nullptr, NN);

    for (int i = 0; i < 3; ++i) {
        // s = t + sum relu(t[src] + bond)   (writes h buffer as s)
        msg_csr_kernel<<<4096, 256, 0, stream>>>(
            t, src_sorted, row_ptr, eas,
            bondW + (long)i * BOND_DIM * DD, bondB + (long)i * DD, s);

        // z1 = s @ W1 + b1   [per-block partial stats -> pz1]
        gemm_mfma<16, 4, 3, true, true><<<NBLK, 256, 0, stream>>>(
            s, nullptr, nullptr, W1f + (long)i * 4 * 16 * 64 * 8,
            b1 + (long)i * 256, z1, pz1, NN);
        bn_finalize_p<<<256, 64, 0, stream>>>(pz1, NBLK, 256,
            g1 + (long)i * 256, be1 + (long)i * 256, 1.f / NN, sc1, sh1);

        // h = relu(bn(z1)) @ W2 + b2   [per-block partial stats -> ph]
        gemm_mfma<8, 8, 2, false, true><<<NBLK, 256, 0, stream>>>(
            z1, sc1, sh1, W2f + (long)i * 8 * 8 * 64 * 8,
            b2 + (long)i * DD, h, ph, NN);
        bn_finalize_p<<<128, 64, 0, stream>>>(ph, NBLK, 128,
            gout + (long)i * DD, bout + (long)i * DD, 1.f / NN, sc2, sh2);

        if (i < 2)
            transform_kernel<<<(int)(((long)NN * DD / 4 + 255) / 256), 256, 0, stream>>>(h, sc2, sh2, t);
    }

    pool_kernel<<<GG, DD, 0, stream>>>(h, sc2, sh2, batch, flag, NN, out);
}

// Round 6
// 779.529 us; speedup vs baseline: 1.2984x; 1.2984x over previous
//
#include <hip/hip_runtime.h>
#include <hip/hip_bf16.h>

#define NN 100000
#define EE 400000
#define GG 4096
#define DD 128
#define ATOM_DIM 101
#define BOND_DIM 11
#define EAP 12    // padded bond-feature stride (48B)
#define GEMM_GRID 512

typedef __attribute__((ext_vector_type(8))) short bf16x8;
typedef __attribute__((ext_vector_type(4))) float f32x4;
typedef __attribute__((ext_vector_type(2))) float f32x2;

__device__ __forceinline__ float b2f(short s) {
    unsigned u = ((unsigned)(unsigned short)s) << 16;
    float f; __builtin_memcpy(&f, &u, 4); return f;
}
__device__ __forceinline__ unsigned short f2b(float f) {
    unsigned u; __builtin_memcpy(&u, &f, 4);
    u += 0x7FFFu + ((u >> 16) & 1u);          // RNE
    return (unsigned short)(u >> 16);
}

// ---------------- index dtype detection (int32 vs int64) ----------------
__global__ void detect64_kernel(const void* ei, int npairs, int* flag) {
    const int* p = (const int*)ei;
    int any = 0;
    for (int i = 1; i < 2 * npairs; i += 2) any |= p[i];
    *flag = (any == 0) ? 1 : 0;
}
__device__ __forceinline__ int getIdx(const void* p, long i, int is64) {
    if (is64) return (int)(((const long long*)p)[i]);
    return ((const int*)p)[i];
}

// ---------------- counting sort by dst ----------------
__global__ __launch_bounds__(256) void hist_kernel(
    const void* __restrict__ eidx, const int* __restrict__ flag, int* __restrict__ counts) {
    int e = blockIdx.x * 256 + threadIdx.x;
    if (e >= EE) return;
    int is64 = *flag;
    int dn = getIdx(eidx, (long)EE + e, is64);
    atomicAdd(&counts[dn], 1);
}

__global__ __launch_bounds__(256) void scan1_kernel(
    const int* __restrict__ counts, int* __restrict__ tmp, int* __restrict__ bsum, int n) {
    __shared__ int sd[256];
    const int tid = threadIdx.x;
    int i = blockIdx.x * 256 + tid;
    int v = (i < n) ? counts[i] : 0;
    sd[tid] = v; __syncthreads();
    #pragma unroll
    for (int off = 1; off < 256; off <<= 1) {
        int a = (tid >= off) ? sd[tid - off] : 0;
        __syncthreads();
        sd[tid] += a;
        __syncthreads();
    }
    if (i < n) tmp[i] = sd[tid] - v;
    if (tid == 255) bsum[blockIdx.x] = sd[255];
}

__global__ __launch_bounds__(512) void scan2_kernel(
    const int* __restrict__ bsum, int* __restrict__ bsumx, int nb) {
    __shared__ int sd[512];
    const int tid = threadIdx.x;
    int v = (tid < nb) ? bsum[tid] : 0;
    sd[tid] = v; __syncthreads();
    #pragma unroll
    for (int off = 1; off < 512; off <<= 1) {
        int a = (tid >= off) ? sd[tid - off] : 0;
        __syncthreads();
        sd[tid] += a;
        __syncthreads();
    }
    if (tid < nb) bsumx[tid] = sd[tid] - v;
}

__global__ __launch_bounds__(256) void scan3_kernel(
    const int* __restrict__ tmp, const int* __restrict__ bsumx,
    int* __restrict__ row_ptr, int n) {
    int i = blockIdx.x * 256 + threadIdx.x;
    if (i < n) row_ptr[i] = tmp[i] + bsumx[blockIdx.x];
    if (i == 0) row_ptr[n] = EE;
}

__global__ __launch_bounds__(256) void scatter_kernel(
    const void* __restrict__ eidx, const int* __restrict__ flag,
    const float* __restrict__ ea, const int* __restrict__ row_ptr,
    int* __restrict__ cursor, int* __restrict__ src_sorted, float* __restrict__ eas) {
    int e = blockIdx.x * 256 + threadIdx.x;
    if (e >= EE) return;
    int is64 = *flag;
    int dn = getIdx(eidx, (long)EE + e, is64);
    int sv = getIdx(eidx, e, is64);
    int pos = row_ptr[dn] + atomicAdd(&cursor[dn], 1);
    src_sorted[pos] = sv;
    const float* sp = ea + (long)e * BOND_DIM;
    float* dp = eas + (long)pos * EAP;
    #pragma unroll
    for (int k = 0; k < BOND_DIM; ++k) dp[k] = sp[k];
    dp[11] = 0.f;
}

// ---------------- fused transform + message + aggregate (CSR) ----------------
// t(v) = sc? relu(h[v]*sc+sh) : h[v]          (BN of prev layer applied inline)
// s[n] = bf16( t(n) + sum_{e in N(n)} relu(t(src) + ea[e] @ bw + bb) )
__global__ __launch_bounds__(256) void msg_csr_kernel(
    const float* __restrict__ h,
    const float* __restrict__ sc, const float* __restrict__ sh,
    const int* __restrict__ src_sorted, const int* __restrict__ row_ptr,
    const float* __restrict__ eas,
    const float* __restrict__ bw,   // [11][128]
    const float* __restrict__ bb,   // [128]
    unsigned short* __restrict__ sout)
{
    const int tid = threadIdx.x;
    const int wave = tid >> 6, lane = tid & 63;
    const int d0 = lane * 2;
    float wk0[BOND_DIM], wk1[BOND_DIM];
    #pragma unroll
    for (int k = 0; k < BOND_DIM; ++k) {
        f32x2 wv = *(const f32x2*)(bw + k * DD + d0);
        wk0[k] = wv.x; wk1[k] = wv.y;
    }
    f32x2 bbv = *(const f32x2*)(bb + d0);
    const bool aff = (sc != nullptr);
    float sc0 = 1.f, sc1v = 1.f, sh0 = 0.f, sh1v = 0.f;
    if (aff) { sc0 = sc[d0]; sc1v = sc[d0 + 1]; sh0 = sh[d0]; sh1v = sh[d0 + 1]; }

    for (int n = blockIdx.x * 4 + wave; n < NN; n += gridDim.x * 4) {
        const int e0 = row_ptr[n], e1 = row_ptr[n + 1];
        float a0 = 0.f, a1 = 0.f;
        int e = e0;
        for (; e + 2 <= e1; e += 2) {
            int sv0 = src_sorted[e];
            int sv1 = src_sorted[e + 1];
            f32x2 ha = *(const f32x2*)(h + (long)sv0 * DD + d0);
            f32x2 hb = *(const f32x2*)(h + (long)sv1 * DD + d0);
            float fa0 = ha.x, fa1 = ha.y, fb0 = hb.x, fb1 = hb.y;
            if (aff) {
                fa0 = fmaxf(fa0 * sc0 + sh0, 0.f); fa1 = fmaxf(fa1 * sc1v + sh1v, 0.f);
                fb0 = fmaxf(fb0 * sc0 + sh0, 0.f); fb1 = fmaxf(fb1 * sc1v + sh1v, 0.f);
            }
            const float* epa = eas + (long)e * EAP;
            const float* epb = epa + EAP;
            f32x4 a0v = *(const f32x4*)epa, a1v = *(const f32x4*)(epa + 4), a2v = *(const f32x4*)(epa + 8);
            f32x4 b0v = *(const f32x4*)epb, b1v = *(const f32x4*)(epb + 4), b2v = *(const f32x4*)(epb + 8);
            float eva[12] = {a0v.x, a0v.y, a0v.z, a0v.w, a1v.x, a1v.y, a1v.z, a1v.w, a2v.x, a2v.y, a2v.z, a2v.w};
            float evb[12] = {b0v.x, b0v.y, b0v.z, b0v.w, b1v.x, b1v.y, b1v.z, b1v.w, b2v.x, b2v.y, b2v.z, b2v.w};
            float ca0 = bbv.x, ca1 = bbv.y, cb0 = bbv.x, cb1 = bbv.y;
            #pragma unroll
            for (int k = 0; k < BOND_DIM; ++k) {
                ca0 = fmaf(eva[k], wk0[k], ca0);
                ca1 = fmaf(eva[k], wk1[k], ca1);
                cb0 = fmaf(evb[k], wk0[k], cb0);
                cb1 = fmaf(evb[k], wk1[k], cb1);
            }
            a0 += fmaxf(fa0 + ca0, 0.f);
            a1 += fmaxf(fa1 + ca1, 0.f);
            a0 += fmaxf(fb0 + cb0, 0.f);
            a1 += fmaxf(fb1 + cb1, 0.f);
        }
        if (e < e1) {
            int sv = src_sorted[e];
            f32x2 hv = *(const f32x2*)(h + (long)sv * DD + d0);
            float f0 = hv.x, f1 = hv.y;
            if (aff) {
                f0 = fmaxf(f0 * sc0 + sh0, 0.f); f1 = fmaxf(f1 * sc1v + sh1v, 0.f);
            }
            const float* ep = eas + (long)e * EAP;
            f32x4 ev0 = *(const f32x4*)ep, ev1 = *(const f32x4*)(ep + 4), ev2 = *(const f32x4*)(ep + 8);
            float ev[12] = {ev0.x, ev0.y, ev0.z, ev0.w, ev1.x, ev1.y, ev1.z, ev1.w, ev2.x, ev2.y, ev2.z, ev2.w};
            float c0 = bbv.x, c1 = bbv.y;
            #pragma unroll
            for (int k = 0; k < BOND_DIM; ++k) {
                c0 = fmaf(ev[k], wk0[k], c0);
                c1 = fmaf(ev[k], wk1[k], c1);
            }
            a0 += fmaxf(f0 + c0, 0.f);
            a1 += fmaxf(f1 + c1, 0.f);
        }
        f32x2 tn = *(const f32x2*)(h + (long)n * DD + d0);
        float t0 = tn.x, t1 = tn.y;
        if (aff) {
            t0 = fmaxf(t0 * sc0 + sh0, 0.f); t1 = fmaxf(t1 * sc1v + sh1v, 0.f);
        }
        unsigned pk = (unsigned)f2b(t0 + a0) | ((unsigned)f2b(t1 + a1) << 16);
        *(unsigned*)(sout + (long)n * DD + d0) = pk;
    }
}

// ---------------- weight pre-pack: W[K][N] f32 -> Wf[ks][f][lane][8] bf16 ----
__global__ void pack_w(const float* __restrict__ W, unsigned short* __restrict__ Wf,
                       int Kact, int N, int KSTEPS) {
    int idx = blockIdx.x * blockDim.x + threadIdx.x;
    int NF = N >> 4;
    int total = KSTEPS * NF * 64;
    if (idx >= total) return;
    int l = idx & 63;
    int f = (idx >> 6) % NF;
    int ks = idx / (64 * NF);
    int col = f * 16 + (l & 15);
    int k0 = ks * 32 + (l >> 4) * 8;
    bf16x8 v;
    #pragma unroll
    for (int j = 0; j < 8; ++j) {
        int k = k0 + j;
        v[j] = (k < Kact) ? (short)f2b(W[(long)k * N + col]) : (short)0;
    }
    *(bf16x8*)(Wf + (long)idx * 8) = v;
}

// ---------------- x f32 [N,101] -> xb bf16 [N,128] zero-padded ----------------
__global__ void pack_x(const float* __restrict__ x, unsigned short* __restrict__ xb) {
    const long total = (long)NN * 128;
    for (long i = (long)blockIdx.x * blockDim.x + threadIdx.x; i < total;
         i += (long)gridDim.x * blockDim.x) {
        int col = (int)(i & 127);
        long row = i >> 7;
        xb[i] = (col < ATOM_DIM) ? f2b(x[row * ATOM_DIM + col]) : (unsigned short)0;
    }
}

// ---------------- register-resident-B MFMA GEMM (no LDS staging, no barriers) ----
// Grid GEMM_GRID blocks x 4 waves. Block owns N-half `half`, strides over M-tiles.
// MODE 0: A bf16 plain.  MODE 2: A = bf16(relu(A*sc+sh)) applied in-register.
template<int NF, int KSTEPS, int NHALVES, int MODE, bool OUT_BF16, bool STATS>
__global__ __launch_bounds__(256, 2) void gemm_reg(
    const unsigned short* __restrict__ A,   // [M][K] bf16
    const float* __restrict__ sc, const float* __restrict__ sh,
    const unsigned short* __restrict__ Wf,  // packed [KSTEPS][NFtot][64][8]
    const float* __restrict__ bias,         // [NFtot*16]
    void* __restrict__ outp,
    float* __restrict__ partial,            // [GEMM_GRID][2*NF*16]
    int M)
{
    constexpr int K = KSTEPS * 32;
    constexpr int NCb = NF * 16;            // cols this block
    constexpr int NFtot = NF * NHALVES;

    __shared__ float s_sc[(MODE == 2) ? K : 1];
    __shared__ float s_sh[(MODE == 2) ? K : 1];
    __shared__ float s_ps[STATS ? 2 * NCb : 1];

    const int tid = threadIdx.x;
    const int wave = tid >> 6, l = tid & 63;
    const int kg = (l >> 4) * 8;
    const int half = (NHALVES > 1) ? (blockIdx.x & (NHALVES - 1)) : 0;
    const int col0 = half * NCb;

    if (MODE == 2 || STATS) {
        if (MODE == 2) {
            for (int i = tid; i < K; i += 256) { s_sc[i] = sc[i]; s_sh[i] = sh[i]; }
        }
        if (STATS) {
            for (int i = tid; i < 2 * NCb; i += 256) s_ps[i] = 0.f;
        }
        __syncthreads();
    }

    // B panel resident in registers (loaded once per block lifetime)
    bf16x8 bfr[KSTEPS][NF];
    {
        const bf16x8* wp = (const bf16x8*)Wf;
        #pragma unroll
        for (int ks = 0; ks < KSTEPS; ++ks)
            #pragma unroll
            for (int f = 0; f < NF; ++f)
                bfr[ks][f] = wp[((long)ks * NFtot + half * NF + f) * 64 + l];
    }

    float bb[NF];
    #pragma unroll
    for (int f = 0; f < NF; ++f) bb[f] = bias[col0 + f * 16 + (l & 15)];

    float ssum[NF], ssq[NF];
    #pragma unroll
    for (int f = 0; f < NF; ++f) { ssum[f] = 0.f; ssq[f] = 0.f; }

    const int MT = (M + 63) >> 6;
    const int bstep = gridDim.x / NHALVES;
    int mt = blockIdx.x / NHALVES;

    bf16x8 ldA[KSTEPS], ldB[KSTEPS];
    {
        int rr = mt * 64 + wave * 16 + (l & 15);
        int rc = rr < M ? rr : M - 1;
        const unsigned short* ap = A + (long)rc * K + kg;
        #pragma unroll
        for (int ks = 0; ks < KSTEPS; ++ks) ldA[ks] = *(const bf16x8*)(ap + ks * 32);
    }

    for (; mt < MT; mt += bstep) {
        const int nxt = mt + bstep;
        if (nxt < MT) {   // prefetch next A tile (flies during transform+MFMA)
            int rr = nxt * 64 + wave * 16 + (l & 15);
            int rc = rr < M ? rr : M - 1;
            const unsigned short* ap = A + (long)rc * K + kg;
            #pragma unroll
            for (int ks = 0; ks < KSTEPS; ++ks) ldB[ks] = *(const bf16x8*)(ap + ks * 32);
        }

        if (MODE == 2) {  // in-register BN + relu + re-round
            #pragma unroll
            for (int ks = 0; ks < KSTEPS; ++ks) {
                f32x4 s0 = *(const f32x4*)&s_sc[ks * 32 + kg];
                f32x4 s1 = *(const f32x4*)&s_sc[ks * 32 + kg + 4];
                f32x4 h0 = *(const f32x4*)&s_sh[ks * 32 + kg];
                f32x4 h1 = *(const f32x4*)&s_sh[ks * 32 + kg + 4];
                float sv[8] = {s0.x, s0.y, s0.z, s0.w, s1.x, s1.y, s1.z, s1.w};
                float hv[8] = {h0.x, h0.y, h0.z, h0.w, h1.x, h1.y, h1.z, h1.w};
                #pragma unroll
                for (int j = 0; j < 8; ++j) {
                    float v = fmaxf(b2f(ldA[ks][j]) * sv[j] + hv[j], 0.f);
                    ldA[ks][j] = (short)f2b(v);
                }
            }
        }

        f32x4 acc[NF];
        #pragma unroll
        for (int f = 0; f < NF; ++f) acc[f] = (f32x4){0.f, 0.f, 0.f, 0.f};
        #pragma unroll
        for (int ks = 0; ks < KSTEPS; ++ks)
            #pragma unroll
            for (int f = 0; f < NF; ++f)
                acc[f] = __builtin_amdgcn_mfma_f32_16x16x32_bf16(ldA[ks], bfr[ks][f], acc[f], 0, 0, 0);

        const int r0 = mt * 64 + wave * 16;
        #pragma unroll
        for (int f = 0; f < NF; ++f) {
            const int col = col0 + f * 16 + (l & 15);
            #pragma unroll
            for (int j = 0; j < 4; ++j) {
                int r = r0 + (l >> 4) * 4 + j;
                if (r < M) {
                    float v = acc[f][j] + bb[f];
                    if (OUT_BF16) ((unsigned short*)outp)[(long)r * (NCb * NHALVES) + col] = f2b(v);
                    else          ((float*)outp)[(long)r * (NCb * NHALVES) + col] = v;
                    if (STATS) { ssum[f] += v; ssq[f] += v * v; }
                }
            }
        }

        #pragma unroll
        for (int ks = 0; ks < KSTEPS; ++ks) ldA[ks] = ldB[ks];
    }

    if (STATS) {
        #pragma unroll
        for (int f = 0; f < NF; ++f) {
            float s = ssum[f], q = ssq[f];
            s += __shfl_xor(s, 16); s += __shfl_xor(s, 32);
            q += __shfl_xor(q, 16); q += __shfl_xor(q, 32);
            if (l < 16) {
                atomicAdd(&s_ps[f * 16 + l], s);
                atomicAdd(&s_ps[NCb + f * 16 + l], q);
            }
        }
        __syncthreads();
        float* pb = partial + (long)blockIdx.x * 2 * NCb;
        for (int i = tid; i < 2 * NCb; i += 256) pb[i] = s_ps[i];
    }
}

// ---------------- BN finalize from per-block partials ----------------
// grid = C (= ncb*halves); block b of the gemm covered cols [ (b%halves)*ncb, +ncb )
__global__ __launch_bounds__(64) void bn_finalize_p(
    const float* __restrict__ partial, int nblk, int ncb, int halves,
    const float* __restrict__ gamma, const float* __restrict__ beta,
    float invN, float* __restrict__ sc, float* __restrict__ sh)
{
    const int c = blockIdx.x;
    const int half = c / ncb, cl = c % ncb;
    const int t = threadIdx.x;
    const int nk = nblk / halves;
    float s = 0.f, q = 0.f;
    for (int k = t; k < nk; k += 64) {
        const float* pb = partial + (long)(half + k * halves) * 2 * ncb;
        s += pb[cl];
        q += pb[ncb + cl];
    }
    #pragma unroll
    for (int off = 1; off < 64; off <<= 1) {
        s += __shfl_xor(s, off);
        q += __shfl_xor(q, off);
    }
    if (t == 0) {
        float m = s * invN;
        float v = q * invN - m * m;
        float g = gamma[c] * rsqrtf(v + 1e-5f);
        sc[c] = g;
        sh[c] = beta[c] - m * g;
    }
}

// ---------------- pooling ----------------
__global__ __launch_bounds__(128) void pool_kernel(
    const float* __restrict__ hraw,
    const float* __restrict__ sc, const float* __restrict__ sh,
    const void* __restrict__ batchp, const int* __restrict__ flag,
    int Nn, float* __restrict__ out)
{
    const int g = blockIdx.x;
    const int t = threadIdx.x;
    const int is64 = *flag;
    int lo = 0, hi = Nn;
    while (lo < hi) { int mid = (lo + hi) >> 1; if (getIdx(batchp, mid, is64) < g) lo = mid + 1; else hi = mid; }
    const int s0 = lo;
    hi = Nn;
    while (lo < hi) { int mid = (lo + hi) >> 1; if (getIdx(batchp, mid, is64) < g + 1) lo = mid + 1; else hi = mid; }
    const int s1 = lo;
    float acc = 0.f;
    for (int r = s0; r < s1; ++r) acc += hraw[(long)r * DD + t];
    const int cnt = s1 - s0;
    float v = 0.f;
    if (cnt > 0) v = (acc / (float)cnt) * sc[t] + sh[t];
    out[(long)g * DD + t] = v;
}

// ---------------- launch ----------------
extern "C" void kernel_launch(void* const* d_in, const int* in_sizes, int n_in,
                              void* d_out, int out_size, void* d_ws, size_t ws_size,
                              hipStream_t stream)
{
    const float* x     = (const float*)d_in[0];
    const float* ea    = (const float*)d_in[1];
    const float* embW  = (const float*)d_in[2];
    const float* embB  = (const float*)d_in[3];
    const float* bondW = (const float*)d_in[4];
    const float* bondB = (const float*)d_in[5];
    const float* W1    = (const float*)d_in[6];
    const float* b1    = (const float*)d_in[7];
    const float* g1    = (const float*)d_in[8];
    const float* be1   = (const float*)d_in[9];
    const float* W2    = (const float*)d_in[10];
    const float* b2    = (const float*)d_in[11];
    const float* gout  = (const float*)d_in[12];
    const float* bout  = (const float*)d_in[13];
    const void*  eidx  = d_in[14];
    const void*  batch = d_in[15];
    float* out = (float*)d_out;

    char* w = (char*)d_ws;
    float* h    = (float*)w;                    w += (long)NN * DD * 4;        // 51.2MB
    unsigned short* s   = (unsigned short*)w;   w += (long)NN * DD * 2;        // 25.6MB
    unsigned short* z1  = (unsigned short*)w;   w += (long)NN * 256 * 2;       // 51.2MB
    unsigned short* xb  = z1;   // alias: consumed by emb gemm before z1 written
    float* eas  = (float*)w;                    w += (long)EE * EAP * 4;       // 19.2MB
    int* src_sorted = (int*)w;                  w += (long)EE * 4;             // 1.6MB
    int* row_ptr    = (int*)w;                  w += (long)(NN + 1) * 4;
    int* counts     = (int*)w;                  w += (long)NN * 4;
    int* tmp        = (int*)w;                  w += (long)NN * 4;
    int* bsum       = (int*)w;                  w += 1024 * 4;
    int* bsumx      = (int*)w;                  w += 1024 * 4;
    float* partial  = (float*)w;                w += (long)GEMM_GRID * 512 * 4; // 1MB
    float* sc1  = (float*)w;                    w += 256 * 4;
    float* sh1  = (float*)w;                    w += 256 * 4;
    float* sc2  = (float*)w;                    w += 128 * 4;
    float* sh2  = (float*)w;                    w += 128 * 4;
    unsigned short* embWf = (unsigned short*)w; w += 4 * 8  * 64 * 8 * 2;
    unsigned short* W1f   = (unsigned short*)w; w += 3L * 4 * 16 * 64 * 8 * 2;
    unsigned short* W2f   = (unsigned short*)w; w += 3L * 8 * 8  * 64 * 8 * 2;
    int* flag = (int*)w;

    detect64_kernel<<<1, 1, 0, stream>>>(eidx, 256, flag);

    // pre-pack weights / x
    pack_x<<<4096, 256, 0, stream>>>(x, xb);
    pack_w<<<8, 256, 0, stream>>>(embW, embWf, ATOM_DIM, 128, 4);
    for (int i = 0; i < 3; ++i) {
        pack_w<<<16, 256, 0, stream>>>(W1 + (long)i * 128 * 256, W1f + (long)i * 4 * 16 * 64 * 8, 128, 256, 4);
        pack_w<<<16, 256, 0, stream>>>(W2 + (long)i * 256 * 128, W2f + (long)i * 8 * 8 * 64 * 8, 256, 128, 8);
    }

    // counting sort of edges by dst -> CSR
    const int eblocks = (EE + 255) / 256;
    const int nb = (NN + 255) / 256;
    hipMemsetAsync(counts, 0, (size_t)NN * 4, stream);
    hist_kernel<<<eblocks, 256, 0, stream>>>(eidx, flag, counts);
    scan1_kernel<<<nb, 256, 0, stream>>>(counts, tmp, bsum, NN);
    scan2_kernel<<<1, 512, 0, stream>>>(bsum, bsumx, nb);
    scan3_kernel<<<nb, 256, 0, stream>>>(tmp, bsumx, row_ptr, NN);
    hipMemsetAsync(counts, 0, (size_t)NN * 4, stream);
    scatter_kernel<<<eblocks, 256, 0, stream>>>(eidx, flag, ea, row_ptr, counts, src_sorted, eas);

    // h0 = x @ embW + embB   (f32)
    gemm_reg<8, 4, 1, 0, false, false><<<GEMM_GRID, 256, 0, stream>>>(
        xb, nullptr, nullptr, embWf, embB, h, nullptr, NN);

    const float* scin = nullptr;
    const float* shin = nullptr;

    for (int i = 0; i < 3; ++i) {
        // s = bf16( t + sum relu(t[src] + bond) ),  t = bn_relu(h) applied inline
        msg_csr_kernel<<<4096, 256, 0, stream>>>(
            h, scin, shin, src_sorted, row_ptr, eas,
            bondW + (long)i * BOND_DIM * DD, bondB + (long)i * DD, s);

        // z1 = s @ W1 + b1   (bf16 out, per-block stats)
        gemm_reg<8, 4, 2, 0, true, true><<<GEMM_GRID, 256, 0, stream>>>(
            s, nullptr, nullptr, W1f + (long)i * 4 * 16 * 64 * 8,
            b1 + (long)i * 256, z1, partial, NN);
        bn_finalize_p<<<256, 64, 0, stream>>>(partial, GEMM_GRID, 128, 2,
            g1 + (long)i * 256, be1 + (long)i * 256, 1.f / NN, sc1, sh1);

        // h = relu(bn(z1)) @ W2 + b2   (f32 out, per-block stats)
        gemm_reg<4, 8, 2, 2, false, true><<<GEMM_GRID, 256, 0, stream>>>(
            z1, sc1, sh1, W2f + (long)i * 8 * 8 * 64 * 8,
            b2 + (long)i * DD, h, partial, NN);
        bn_finalize_p<<<128, 64, 0, stream>>>(partial, GEMM_GRID, 64, 2,
            gout + (long)i * DD, bout + (long)i * DD, 1.f / NN, sc2, sh2);

        scin = sc2; shin = sh2;
    }

    pool_kernel<<<GG, DD, 0, stream>>>(h, sc2, sh2, batch, flag, NN, out);
}

// Round 7
// 605.702 us; speedup vs baseline: 1.6710x; 1.2870x over previous
//
#include <hip/hip_runtime.h>
#include <hip/hip_bf16.h>

#define NN 100000
#define EE 400000
#define GG 4096
#define DD 128
#define ATOM_DIM 101
#define BOND_DIM 11
#define EAP 12    // padded bond-feature stride (48B)
#define GEMM_GRID 512

typedef __attribute__((ext_vector_type(8))) short bf16x8;
typedef __attribute__((ext_vector_type(4))) float f32x4;
typedef __attribute__((ext_vector_type(2))) float f32x2;

__device__ __forceinline__ float b2f(short s) {
    unsigned u = ((unsigned)(unsigned short)s) << 16;
    float f; __builtin_memcpy(&f, &u, 4); return f;
}
__device__ __forceinline__ unsigned short f2b(float f) {
    unsigned u; __builtin_memcpy(&u, &f, 4);
    u += 0x7FFFu + ((u >> 16) & 1u);          // RNE
    return (unsigned short)(u >> 16);
}

// ---------------- index dtype detection (int32 vs int64) ----------------
__global__ void detect64_kernel(const void* ei, int npairs, int* flag) {
    const int* p = (const int*)ei;
    int any = 0;
    for (int i = 1; i < 2 * npairs; i += 2) any |= p[i];
    *flag = (any == 0) ? 1 : 0;
}
__device__ __forceinline__ int getIdx(const void* p, long i, int is64) {
    if (is64) return (int)(((const long long*)p)[i]);
    return ((const int*)p)[i];
}

// ---------------- counting sort by dst ----------------
__global__ __launch_bounds__(256) void hist_kernel(
    const void* __restrict__ eidx, const int* __restrict__ flag, int* __restrict__ counts) {
    int e = blockIdx.x * 256 + threadIdx.x;
    if (e >= EE) return;
    int is64 = *flag;
    int dn = getIdx(eidx, (long)EE + e, is64);
    atomicAdd(&counts[dn], 1);
}

__global__ __launch_bounds__(256) void scan1_kernel(
    const int* __restrict__ counts, int* __restrict__ tmp, int* __restrict__ bsum, int n) {
    __shared__ int sd[256];
    const int tid = threadIdx.x;
    int i = blockIdx.x * 256 + tid;
    int v = (i < n) ? counts[i] : 0;
    sd[tid] = v; __syncthreads();
    #pragma unroll
    for (int off = 1; off < 256; off <<= 1) {
        int a = (tid >= off) ? sd[tid - off] : 0;
        __syncthreads();
        sd[tid] += a;
        __syncthreads();
    }
    if (i < n) tmp[i] = sd[tid] - v;
    if (tid == 255) bsum[blockIdx.x] = sd[255];
}

__global__ __launch_bounds__(512) void scan2_kernel(
    const int* __restrict__ bsum, int* __restrict__ bsumx, int nb) {
    __shared__ int sd[512];
    const int tid = threadIdx.x;
    int v = (tid < nb) ? bsum[tid] : 0;
    sd[tid] = v; __syncthreads();
    #pragma unroll
    for (int off = 1; off < 512; off <<= 1) {
        int a = (tid >= off) ? sd[tid - off] : 0;
        __syncthreads();
        sd[tid] += a;
        __syncthreads();
    }
    if (tid < nb) bsumx[tid] = sd[tid] - v;
}

__global__ __launch_bounds__(256) void scan3_kernel(
    const int* __restrict__ tmp, const int* __restrict__ bsumx,
    int* __restrict__ row_ptr, int n) {
    int i = blockIdx.x * 256 + threadIdx.x;
    if (i < n) row_ptr[i] = tmp[i] + bsumx[blockIdx.x];
    if (i == 0) row_ptr[n] = EE;
}

__global__ __launch_bounds__(256) void scatter_kernel(
    const void* __restrict__ eidx, const int* __restrict__ flag,
    const float* __restrict__ ea, const int* __restrict__ row_ptr,
    int* __restrict__ cursor, int* __restrict__ src_sorted, float* __restrict__ eas) {
    int e = blockIdx.x * 256 + threadIdx.x;
    if (e >= EE) return;
    int is64 = *flag;
    int dn = getIdx(eidx, (long)EE + e, is64);
    int sv = getIdx(eidx, e, is64);
    int pos = row_ptr[dn] + atomicAdd(&cursor[dn], 1);
    src_sorted[pos] = sv;
    const float* sp = ea + (long)e * BOND_DIM;
    float* dp = eas + (long)pos * EAP;
    #pragma unroll
    for (int k = 0; k < BOND_DIM; ++k) dp[k] = sp[k];
    dp[11] = 0.f;
}

// ---------------- fused transform + message + aggregate (CSR) ----------------
// t(v) = sc? relu(h[v]*sc+sh) : h[v]
// s[n] = bf16( t(n) + sum_{e in N(n)} relu(t(src) + ea[e] @ bw + bb) )
__global__ __launch_bounds__(256) void msg_csr_kernel(
    const float* __restrict__ h,
    const float* __restrict__ sc, const float* __restrict__ sh,
    const int* __restrict__ src_sorted, const int* __restrict__ row_ptr,
    const float* __restrict__ eas,
    const float* __restrict__ bw,   // [11][128]
    const float* __restrict__ bb,   // [128]
    unsigned short* __restrict__ sout)
{
    const int tid = threadIdx.x;
    const int wave = tid >> 6, lane = tid & 63;
    const int d0 = lane * 2;
    float wk0[BOND_DIM], wk1[BOND_DIM];
    #pragma unroll
    for (int k = 0; k < BOND_DIM; ++k) {
        f32x2 wv = *(const f32x2*)(bw + k * DD + d0);
        wk0[k] = wv.x; wk1[k] = wv.y;
    }
    f32x2 bbv = *(const f32x2*)(bb + d0);
    const bool aff = (sc != nullptr);
    float sc0 = 1.f, sc1v = 1.f, sh0 = 0.f, sh1v = 0.f;
    if (aff) { sc0 = sc[d0]; sc1v = sc[d0 + 1]; sh0 = sh[d0]; sh1v = sh[d0 + 1]; }

    for (int n = blockIdx.x * 4 + wave; n < NN; n += gridDim.x * 4) {
        const int e0 = row_ptr[n], e1 = row_ptr[n + 1];
        float a0 = 0.f, a1 = 0.f;
        int e = e0;
        for (; e + 2 <= e1; e += 2) {
            int sv0 = src_sorted[e];
            int sv1 = src_sorted[e + 1];
            f32x2 ha = *(const f32x2*)(h + (long)sv0 * DD + d0);
            f32x2 hb = *(const f32x2*)(h + (long)sv1 * DD + d0);
            float fa0 = ha.x, fa1 = ha.y, fb0 = hb.x, fb1 = hb.y;
            if (aff) {
                fa0 = fmaxf(fa0 * sc0 + sh0, 0.f); fa1 = fmaxf(fa1 * sc1v + sh1v, 0.f);
                fb0 = fmaxf(fb0 * sc0 + sh0, 0.f); fb1 = fmaxf(fb1 * sc1v + sh1v, 0.f);
            }
            const float* epa = eas + (long)e * EAP;
            const float* epb = epa + EAP;
            f32x4 a0v = *(const f32x4*)epa, a1v = *(const f32x4*)(epa + 4), a2v = *(const f32x4*)(epa + 8);
            f32x4 b0v = *(const f32x4*)epb, b1v = *(const f32x4*)(epb + 4), b2v = *(const f32x4*)(epb + 8);
            float eva[12] = {a0v.x, a0v.y, a0v.z, a0v.w, a1v.x, a1v.y, a1v.z, a1v.w, a2v.x, a2v.y, a2v.z, a2v.w};
            float evb[12] = {b0v.x, b0v.y, b0v.z, b0v.w, b1v.x, b1v.y, b1v.z, b1v.w, b2v.x, b2v.y, b2v.z, b2v.w};
            float ca0 = bbv.x, ca1 = bbv.y, cb0 = bbv.x, cb1 = bbv.y;
            #pragma unroll
            for (int k = 0; k < BOND_DIM; ++k) {
                ca0 = fmaf(eva[k], wk0[k], ca0);
                ca1 = fmaf(eva[k], wk1[k], ca1);
                cb0 = fmaf(evb[k], wk0[k], cb0);
                cb1 = fmaf(evb[k], wk1[k], cb1);
            }
            a0 += fmaxf(fa0 + ca0, 0.f);
            a1 += fmaxf(fa1 + ca1, 0.f);
            a0 += fmaxf(fb0 + cb0, 0.f);
            a1 += fmaxf(fb1 + cb1, 0.f);
        }
        if (e < e1) {
            int sv = src_sorted[e];
            f32x2 hv = *(const f32x2*)(h + (long)sv * DD + d0);
            float f0 = hv.x, f1 = hv.y;
            if (aff) {
                f0 = fmaxf(f0 * sc0 + sh0, 0.f); f1 = fmaxf(f1 * sc1v + sh1v, 0.f);
            }
            const float* ep = eas + (long)e * EAP;
            f32x4 ev0 = *(const f32x4*)ep, ev1 = *(const f32x4*)(ep + 4), ev2 = *(const f32x4*)(ep + 8);
            float ev[12] = {ev0.x, ev0.y, ev0.z, ev0.w, ev1.x, ev1.y, ev1.z, ev1.w, ev2.x, ev2.y, ev2.z, ev2.w};
            float c0 = bbv.x, c1 = bbv.y;
            #pragma unroll
            for (int k = 0; k < BOND_DIM; ++k) {
                c0 = fmaf(ev[k], wk0[k], c0);
                c1 = fmaf(ev[k], wk1[k], c1);
            }
            a0 += fmaxf(f0 + c0, 0.f);
            a1 += fmaxf(f1 + c1, 0.f);
        }
        f32x2 tn = *(const f32x2*)(h + (long)n * DD + d0);
        float t0 = tn.x, t1 = tn.y;
        if (aff) {
            t0 = fmaxf(t0 * sc0 + sh0, 0.f); t1 = fmaxf(t1 * sc1v + sh1v, 0.f);
        }
        unsigned pk = (unsigned)f2b(t0 + a0) | ((unsigned)f2b(t1 + a1) << 16);
        *(unsigned*)(sout + (long)n * DD + d0) = pk;
    }
}

// ---------------- weight pre-pack: W[K][N] f32 -> Wf[ks][f][lane][8] bf16 ----
__global__ void pack_w(const float* __restrict__ W, unsigned short* __restrict__ Wf,
                       int Kact, int N, int KSTEPS) {
    int idx = blockIdx.x * blockDim.x + threadIdx.x;
    int NF = N >> 4;
    int total = KSTEPS * NF * 64;
    if (idx >= total) return;
    int l = idx & 63;
    int f = (idx >> 6) % NF;
    int ks = idx / (64 * NF);
    int col = f * 16 + (l & 15);
    int k0 = ks * 32 + (l >> 4) * 8;
    bf16x8 v;
    #pragma unroll
    for (int j = 0; j < 8; ++j) {
        int k = k0 + j;
        v[j] = (k < Kact) ? (short)f2b(W[(long)k * N + col]) : (short)0;
    }
    *(bf16x8*)(Wf + (long)idx * 8) = v;
}

// ---------------- x f32 [N,101] -> xb bf16 [N,128] zero-padded ----------------
__global__ void pack_x(const float* __restrict__ x, unsigned short* __restrict__ xb) {
    const long total = (long)NN * 128;
    for (long i = (long)blockIdx.x * blockDim.x + threadIdx.x; i < total;
         i += (long)gridDim.x * blockDim.x) {
        int col = (int)(i & 127);
        long row = i >> 7;
        xb[i] = (col < ATOM_DIM) ? f2b(x[row * ATOM_DIM + col]) : (unsigned short)0;
    }
}

// ---------------- register-resident-B MFMA GEMM ----------------
// XCD-paired halves (blocks b and b+8 share mt and an XCD) + LDS store epilogue
// MODE 0: A bf16 plain.  MODE 2: A = bf16(relu(A*sc+sh)) in-register.
template<int NF, int KSTEPS, int NHALVES, int MODE, bool OUT_BF16, bool STATS>
__global__ __launch_bounds__(256, 2) void gemm_reg(
    const unsigned short* __restrict__ A,   // [M][K] bf16
    const float* __restrict__ sc, const float* __restrict__ sh,
    const unsigned short* __restrict__ Wf,  // packed [KSTEPS][NFtot][64][8]
    const float* __restrict__ bias,         // [NFtot*16]
    void* __restrict__ outp,
    float* __restrict__ partial,            // [GEMM_GRID][2*NF*16]
    int M)
{
    constexpr int K = KSTEPS * 32;
    constexpr int NCb = NF * 16;
    constexpr int NFtot = NF * NHALVES;
    constexpr int NCtot = NCb * NHALVES;
    constexpr int ESZ = OUT_BF16 ? 2 : 4;
    constexpr int RSTRIDE = NCb + (OUT_BF16 ? 8 : 4);   // LDS row stride (elems), keeps rows 16B-aligned
    constexpr int ROWBYTES = NCb * ESZ;
    constexpr int CHUNKS = 64 * ROWBYTES / 16;
    constexpr int CPR = ROWBYTES / 16;

    __shared__ __align__(16) char sOut[64 * RSTRIDE * ESZ];
    __shared__ float s_sc[(MODE == 2) ? K : 1];
    __shared__ float s_sh[(MODE == 2) ? K : 1];
    __shared__ float s_ps[STATS ? 2 * NCb : 1];

    const int tid = threadIdx.x;
    const int wave = tid >> 6, l = tid & 63;
    const int kg = (l >> 4) * 8;

    // XCD-pair swizzle: halves of the same tile land on the same XCD (b, b+8)
    int half, mt;
    if (NHALVES == 2) {
        int b = blockIdx.x;
        half = (b >> 3) & 1;
        mt = (b & 7) | ((b >> 4) << 3);
    } else {
        half = 0; mt = blockIdx.x;
    }
    const int col0 = half * NCb;
    const int bstep = gridDim.x / NHALVES;

    if (MODE == 2 || STATS) {
        if (MODE == 2) {
            for (int i = tid; i < K; i += 256) { s_sc[i] = sc[i]; s_sh[i] = sh[i]; }
        }
        if (STATS) {
            for (int i = tid; i < 2 * NCb; i += 256) s_ps[i] = 0.f;
        }
        __syncthreads();
    }

    // B panel resident in registers
    bf16x8 bfr[KSTEPS][NF];
    {
        const bf16x8* wp = (const bf16x8*)Wf;
        #pragma unroll
        for (int ks = 0; ks < KSTEPS; ++ks)
            #pragma unroll
            for (int f = 0; f < NF; ++f)
                bfr[ks][f] = wp[((long)ks * NFtot + half * NF + f) * 64 + l];
    }

    float bb[NF];
    #pragma unroll
    for (int f = 0; f < NF; ++f) bb[f] = bias[col0 + f * 16 + (l & 15)];

    float ssum[NF], ssq[NF];
    #pragma unroll
    for (int f = 0; f < NF; ++f) { ssum[f] = 0.f; ssq[f] = 0.f; }

    const int MT = (M + 63) >> 6;

    bf16x8 ldA[KSTEPS], ldB[KSTEPS];
    {
        int rr = mt * 64 + wave * 16 + (l & 15);
        int rc = rr < M ? rr : M - 1;
        const unsigned short* ap = A + (long)rc * K + kg;
        #pragma unroll
        for (int ks = 0; ks < KSTEPS; ++ks) ldA[ks] = *(const bf16x8*)(ap + ks * 32);
    }

    for (; mt < MT; mt += bstep) {
        const int nxt = mt + bstep;
        if (nxt < MT) {   // prefetch next A tile
            int rr = nxt * 64 + wave * 16 + (l & 15);
            int rc = rr < M ? rr : M - 1;
            const unsigned short* ap = A + (long)rc * K + kg;
            #pragma unroll
            for (int ks = 0; ks < KSTEPS; ++ks) ldB[ks] = *(const bf16x8*)(ap + ks * 32);
        }

        if (MODE == 2) {  // in-register BN + relu + re-round
            #pragma unroll
            for (int ks = 0; ks < KSTEPS; ++ks) {
                f32x4 s0 = *(const f32x4*)&s_sc[ks * 32 + kg];
                f32x4 s1 = *(const f32x4*)&s_sc[ks * 32 + kg + 4];
                f32x4 h0 = *(const f32x4*)&s_sh[ks * 32 + kg];
                f32x4 h1 = *(const f32x4*)&s_sh[ks * 32 + kg + 4];
                float sv[8] = {s0.x, s0.y, s0.z, s0.w, s1.x, s1.y, s1.z, s1.w};
                float hv[8] = {h0.x, h0.y, h0.z, h0.w, h1.x, h1.y, h1.z, h1.w};
                #pragma unroll
                for (int j = 0; j < 8; ++j) {
                    float v = fmaxf(b2f(ldA[ks][j]) * sv[j] + hv[j], 0.f);
                    ldA[ks][j] = (short)f2b(v);
                }
            }
        }

        f32x4 acc[NF];
        #pragma unroll
        for (int f = 0; f < NF; ++f) acc[f] = (f32x4){0.f, 0.f, 0.f, 0.f};
        #pragma unroll
        for (int ks = 0; ks < KSTEPS; ++ks)
            #pragma unroll
            for (int f = 0; f < NF; ++f)
                acc[f] = __builtin_amdgcn_mfma_f32_16x16x32_bf16(ldA[ks], bfr[ks][f], acc[f], 0, 0, 0);

        // stage C tile into LDS (+stats in registers)
        const int rtile = mt * 64;
        #pragma unroll
        for (int f = 0; f < NF; ++f) {
            const int cl = f * 16 + (l & 15);
            #pragma unroll
            for (int j = 0; j < 4; ++j) {
                const int rl = wave * 16 + (l >> 4) * 4 + j;
                float v = acc[f][j] + bb[f];
                if (OUT_BF16) ((unsigned short*)sOut)[rl * RSTRIDE + cl] = f2b(v);
                else          ((float*)sOut)[rl * RSTRIDE + cl] = v;
                if (STATS && rtile + rl < M) { ssum[f] += v; ssq[f] += v * v; }
            }
        }
        __syncthreads();

        // stream LDS tile out as full-line 16B stores
        const int rmax = M - rtile;
        #pragma unroll
        for (int i = 0; i < CHUNKS / 256; ++i) {
            int c = i * 256 + tid;
            int row = c / CPR;
            int off = (c % CPR) * 16;
            if (row < rmax) {
                f32x4 v = *(const f32x4*)(sOut + row * (RSTRIDE * ESZ) + off);
                char* gp = (char*)outp + ((long)(rtile + row) * NCtot + col0) * ESZ + off;
                *(f32x4*)gp = v;
            }
        }
        __syncthreads();

        #pragma unroll
        for (int ks = 0; ks < KSTEPS; ++ks) ldA[ks] = ldB[ks];
    }

    if (STATS) {
        #pragma unroll
        for (int f = 0; f < NF; ++f) {
            float s = ssum[f], q = ssq[f];
            s += __shfl_xor(s, 16); s += __shfl_xor(s, 32);
            q += __shfl_xor(q, 16); q += __shfl_xor(q, 32);
            if (l < 16) {
                atomicAdd(&s_ps[f * 16 + l], s);
                atomicAdd(&s_ps[NCb + f * 16 + l], q);
            }
        }
        __syncthreads();
        float* pb = partial + (long)blockIdx.x * 2 * NCb;
        for (int i = tid; i < 2 * NCb; i += 256) pb[i] = s_ps[i];
    }
}

// ---------------- BN finalize from per-block partials ----------------
__global__ __launch_bounds__(64) void bn_finalize_p(
    const float* __restrict__ partial, int nblk, int ncb, int halves,
    const float* __restrict__ gamma, const float* __restrict__ beta,
    float invN, float* __restrict__ sc, float* __restrict__ sh)
{
    const int c = blockIdx.x;
    const int t = threadIdx.x;
    // block b covered cols [((b>>3)&1)*ncb, +ncb) when halves==2
    float s = 0.f, q = 0.f;
    for (int b = t; b < nblk; b += 64) {
        int half = (halves == 2) ? ((b >> 3) & 1) : 0;
        if (c / ncb != half) continue;
        const float* pb = partial + (long)b * 2 * ncb;
        s += pb[c % ncb];
        q += pb[ncb + c % ncb];
    }
    #pragma unroll
    for (int off = 1; off < 64; off <<= 1) {
        s += __shfl_xor(s, off);
        q += __shfl_xor(q, off);
    }
    if (t == 0) {
        float m = s * invN;
        float v = q * invN - m * m;
        float g = gamma[c] * rsqrtf(v + 1e-5f);
        sc[c] = g;
        sh[c] = beta[c] - m * g;
    }
}

// ---------------- pooling ----------------
__global__ __launch_bounds__(128) void pool_kernel(
    const float* __restrict__ hraw,
    const float* __restrict__ sc, const float* __restrict__ sh,
    const void* __restrict__ batchp, const int* __restrict__ flag,
    int Nn, float* __restrict__ out)
{
    const int g = blockIdx.x;
    const int t = threadIdx.x;
    const int is64 = *flag;
    int lo = 0, hi = Nn;
    while (lo < hi) { int mid = (lo + hi) >> 1; if (getIdx(batchp, mid, is64) < g) lo = mid + 1; else hi = mid; }
    const int s0 = lo;
    hi = Nn;
    while (lo < hi) { int mid = (lo + hi) >> 1; if (getIdx(batchp, mid, is64) < g + 1) lo = mid + 1; else hi = mid; }
    const int s1 = lo;
    float acc = 0.f;
    for (int r = s0; r < s1; ++r) acc += hraw[(long)r * DD + t];
    const int cnt = s1 - s0;
    float v = 0.f;
    if (cnt > 0) v = (acc / (float)cnt) * sc[t] + sh[t];
    out[(long)g * DD + t] = v;
}

// ---------------- launch ----------------
extern "C" void kernel_launch(void* const* d_in, const int* in_sizes, int n_in,
                              void* d_out, int out_size, void* d_ws, size_t ws_size,
                              hipStream_t stream)
{
    const float* x     = (const float*)d_in[0];
    const float* ea    = (const float*)d_in[1];
    const float* embW  = (const float*)d_in[2];
    const float* embB  = (const float*)d_in[3];
    const float* bondW = (const float*)d_in[4];
    const float* bondB = (const float*)d_in[5];
    const float* W1    = (const float*)d_in[6];
    const float* b1    = (const float*)d_in[7];
    const float* g1    = (const float*)d_in[8];
    const float* be1   = (const float*)d_in[9];
    const float* W2    = (const float*)d_in[10];
    const float* b2    = (const float*)d_in[11];
    const float* gout  = (const float*)d_in[12];
    const float* bout  = (const float*)d_in[13];
    const void*  eidx  = d_in[14];
    const void*  batch = d_in[15];
    float* out = (float*)d_out;

    char* w = (char*)d_ws;
    float* h    = (float*)w;                    w += (long)NN * DD * 4;        // 51.2MB
    unsigned short* s   = (unsigned short*)w;   w += (long)NN * DD * 2;        // 25.6MB
    unsigned short* z1  = (unsigned short*)w;   w += (long)NN * 256 * 2;       // 51.2MB
    unsigned short* xb  = z1;   // alias: consumed by emb gemm before z1 written
    float* eas  = (float*)w;                    w += (long)EE * EAP * 4;       // 19.2MB
    int* src_sorted = (int*)w;                  w += (long)EE * 4;             // 1.6MB
    int* row_ptr    = (int*)w;                  w += (long)(NN + 1) * 4;
    int* counts     = (int*)w;                  w += (long)NN * 4;
    int* tmp        = (int*)w;                  w += (long)NN * 4;
    int* bsum       = (int*)w;                  w += 1024 * 4;
    int* bsumx      = (int*)w;                  w += 1024 * 4;
    float* partial  = (float*)w;                w += (long)GEMM_GRID * 512 * 4; // 1MB
    float* sc1  = (float*)w;                    w += 256 * 4;
    float* sh1  = (float*)w;                    w += 256 * 4;
    float* sc2  = (float*)w;                    w += 128 * 4;
    float* sh2  = (float*)w;                    w += 128 * 4;
    unsigned short* embWf = (unsigned short*)w; w += 4 * 8  * 64 * 8 * 2;
    unsigned short* W1f   = (unsigned short*)w; w += 3L * 4 * 16 * 64 * 8 * 2;
    unsigned short* W2f   = (unsigned short*)w; w += 3L * 8 * 8  * 64 * 8 * 2;
    int* flag = (int*)w;

    detect64_kernel<<<1, 1, 0, stream>>>(eidx, 256, flag);

    // pre-pack weights / x
    pack_x<<<4096, 256, 0, stream>>>(x, xb);
    pack_w<<<8, 256, 0, stream>>>(embW, embWf, ATOM_DIM, 128, 4);
    for (int i = 0; i < 3; ++i) {
        pack_w<<<16, 256, 0, stream>>>(W1 + (long)i * 128 * 256, W1f + (long)i * 4 * 16 * 64 * 8, 128, 256, 4);
        pack_w<<<16, 256, 0, stream>>>(W2 + (long)i * 256 * 128, W2f + (long)i * 8 * 8 * 64 * 8, 256, 128, 8);
    }

    // counting sort of edges by dst -> CSR
    const int eblocks = (EE + 255) / 256;
    const int nb = (NN + 255) / 256;
    hipMemsetAsync(counts, 0, (size_t)NN * 4, stream);
    hist_kernel<<<eblocks, 256, 0, stream>>>(eidx, flag, counts);
    scan1_kernel<<<nb, 256, 0, stream>>>(counts, tmp, bsum, NN);
    scan2_kernel<<<1, 512, 0, stream>>>(bsum, bsumx, nb);
    scan3_kernel<<<nb, 256, 0, stream>>>(tmp, bsumx, row_ptr, NN);
    hipMemsetAsync(counts, 0, (size_t)NN * 4, stream);
    scatter_kernel<<<eblocks, 256, 0, stream>>>(eidx, flag, ea, row_ptr, counts, src_sorted, eas);

    // h0 = x @ embW + embB   (f32)
    gemm_reg<8, 4, 1, 0, false, false><<<GEMM_GRID, 256, 0, stream>>>(
        xb, nullptr, nullptr, embWf, embB, h, nullptr, NN);

    const float* scin = nullptr;
    const float* shin = nullptr;

    for (int i = 0; i < 3; ++i) {
        // s = bf16( t + sum relu(t[src] + bond) ),  t = bn_relu(h) applied inline
        msg_csr_kernel<<<4096, 256, 0, stream>>>(
            h, scin, shin, src_sorted, row_ptr, eas,
            bondW + (long)i * BOND_DIM * DD, bondB + (long)i * DD, s);

        // z1 = s @ W1 + b1   (bf16 out, per-block stats)
        gemm_reg<8, 4, 2, 0, true, true><<<GEMM_GRID, 256, 0, stream>>>(
            s, nullptr, nullptr, W1f + (long)i * 4 * 16 * 64 * 8,
            b1 + (long)i * 256, z1, partial, NN);
        bn_finalize_p<<<256, 64, 0, stream>>>(partial, GEMM_GRID, 128, 2,
            g1 + (long)i * 256, be1 + (long)i * 256, 1.f / NN, sc1, sh1);

        // h = relu(bn(z1)) @ W2 + b2   (f32 out, per-block stats)
        gemm_reg<4, 8, 2, 2, false, true><<<GEMM_GRID, 256, 0, stream>>>(
            z1, sc1, sh1, W2f + (long)i * 8 * 8 * 64 * 8,
            b2 + (long)i * DD, h, partial, NN);
        bn_finalize_p<<<128, 64, 0, stream>>>(partial, GEMM_GRID, 64, 2,
            gout + (long)i * DD, bout + (long)i * DD, 1.f / NN, sc2, sh2);

        scin = sc2; shin = sh2;
    }

    pool_kernel<<<GG, DD, 0, stream>>>(h, sc2, sh2, batch, flag, NN, out);
}

// Round 8
// 594.361 us; speedup vs baseline: 1.7029x; 1.0191x over previous
//
#include <hip/hip_runtime.h>
#include <hip/hip_bf16.h>

#define NN 100000
#define EE 400000
#define GG 4096
#define DD 128
#define ATOM_DIM 101
#define BOND_DIM 11
#define EAP 12    // padded bond-feature stride (48B)
#define GEMM_GRID 512

typedef __attribute__((ext_vector_type(8))) short bf16x8;
typedef __attribute__((ext_vector_type(4))) float f32x4;
typedef __attribute__((ext_vector_type(2))) float f32x2;

__device__ __forceinline__ float b2f(short s) {
    unsigned u = ((unsigned)(unsigned short)s) << 16;
    float f; __builtin_memcpy(&f, &u, 4); return f;
}
__device__ __forceinline__ unsigned short f2b(float f) {
    unsigned u; __builtin_memcpy(&u, &f, 4);
    u += 0x7FFFu + ((u >> 16) & 1u);          // RNE
    return (unsigned short)(u >> 16);
}

// ---------------- index dtype detection (int32 vs int64) ----------------
__global__ void detect64_kernel(const void* ei, int npairs, int* flag) {
    const int* p = (const int*)ei;
    int any = 0;
    for (int i = 1; i < 2 * npairs; i += 2) any |= p[i];
    *flag = (any == 0) ? 1 : 0;
}
__device__ __forceinline__ int getIdx(const void* p, long i, int is64) {
    if (is64) return (int)(((const long long*)p)[i]);
    return ((const int*)p)[i];
}

// ---------------- counting sort by dst ----------------
__global__ __launch_bounds__(256) void hist_kernel(
    const void* __restrict__ eidx, const int* __restrict__ flag, int* __restrict__ counts) {
    int e = blockIdx.x * 256 + threadIdx.x;
    if (e >= EE) return;
    int is64 = *flag;
    int dn = getIdx(eidx, (long)EE + e, is64);
    atomicAdd(&counts[dn], 1);
}

__global__ __launch_bounds__(256) void scan1_kernel(
    const int* __restrict__ counts, int* __restrict__ tmp, int* __restrict__ bsum, int n) {
    __shared__ int sd[256];
    const int tid = threadIdx.x;
    int i = blockIdx.x * 256 + tid;
    int v = (i < n) ? counts[i] : 0;
    sd[tid] = v; __syncthreads();
    #pragma unroll
    for (int off = 1; off < 256; off <<= 1) {
        int a = (tid >= off) ? sd[tid - off] : 0;
        __syncthreads();
        sd[tid] += a;
        __syncthreads();
    }
    if (i < n) tmp[i] = sd[tid] - v;
    if (tid == 255) bsum[blockIdx.x] = sd[255];
}

__global__ __launch_bounds__(512) void scan2_kernel(
    const int* __restrict__ bsum, int* __restrict__ bsumx, int nb) {
    __shared__ int sd[512];
    const int tid = threadIdx.x;
    int v = (tid < nb) ? bsum[tid] : 0;
    sd[tid] = v; __syncthreads();
    #pragma unroll
    for (int off = 1; off < 512; off <<= 1) {
        int a = (tid >= off) ? sd[tid - off] : 0;
        __syncthreads();
        sd[tid] += a;
        __syncthreads();
    }
    if (tid < nb) bsumx[tid] = sd[tid] - v;
}

__global__ __launch_bounds__(256) void scan3_kernel(
    const int* __restrict__ tmp, const int* __restrict__ bsumx,
    int* __restrict__ row_ptr, int n) {
    int i = blockIdx.x * 256 + threadIdx.x;
    if (i < n) row_ptr[i] = tmp[i] + bsumx[blockIdx.x];
    if (i == 0) row_ptr[n] = EE;
}

__global__ __launch_bounds__(256) void scatter_kernel(
    const void* __restrict__ eidx, const int* __restrict__ flag,
    const float* __restrict__ ea, const int* __restrict__ row_ptr,
    int* __restrict__ cursor, int* __restrict__ src_sorted, float* __restrict__ eas) {
    int e = blockIdx.x * 256 + threadIdx.x;
    if (e >= EE) return;
    int is64 = *flag;
    int dn = getIdx(eidx, (long)EE + e, is64);
    int sv = getIdx(eidx, e, is64);
    int pos = row_ptr[dn] + atomicAdd(&cursor[dn], 1);
    src_sorted[pos] = sv;
    const float* sp = ea + (long)e * BOND_DIM;
    float* dp = eas + (long)pos * EAP;
    #pragma unroll
    for (int k = 0; k < BOND_DIM; ++k) dp[k] = sp[k];
    dp[11] = 0.f;
}

// ---------------- fused transform + message + aggregate (CSR) ----------------
// t(v) = sc? relu(h[v]*sc+sh) : h[v]
// s[n] = bf16( t(n) + sum_{e in N(n)} relu(t(src) + ea[e] @ bw + bb) )
__global__ __launch_bounds__(256) void msg_csr_kernel(
    const float* __restrict__ h,
    const float* __restrict__ sc, const float* __restrict__ sh,
    const int* __restrict__ src_sorted, const int* __restrict__ row_ptr,
    const float* __restrict__ eas,
    const float* __restrict__ bw,   // [11][128]
    const float* __restrict__ bb,   // [128]
    unsigned short* __restrict__ sout)
{
    const int tid = threadIdx.x;
    const int wave = tid >> 6, lane = tid & 63;
    const int d0 = lane * 2;
    float wk0[BOND_DIM], wk1[BOND_DIM];
    #pragma unroll
    for (int k = 0; k < BOND_DIM; ++k) {
        f32x2 wv = *(const f32x2*)(bw + k * DD + d0);
        wk0[k] = wv.x; wk1[k] = wv.y;
    }
    f32x2 bbv = *(const f32x2*)(bb + d0);
    const bool aff = (sc != nullptr);
    float sc0 = 1.f, sc1v = 1.f, sh0 = 0.f, sh1v = 0.f;
    if (aff) { sc0 = sc[d0]; sc1v = sc[d0 + 1]; sh0 = sh[d0]; sh1v = sh[d0 + 1]; }

    for (int n = blockIdx.x * 4 + wave; n < NN; n += gridDim.x * 4) {
        const int e0 = row_ptr[n], e1 = row_ptr[n + 1];
        float a0 = 0.f, a1 = 0.f;
        int e = e0;
        for (; e + 2 <= e1; e += 2) {
            int sv0 = src_sorted[e];
            int sv1 = src_sorted[e + 1];
            f32x2 ha = *(const f32x2*)(h + (long)sv0 * DD + d0);
            f32x2 hb = *(const f32x2*)(h + (long)sv1 * DD + d0);
            float fa0 = ha.x, fa1 = ha.y, fb0 = hb.x, fb1 = hb.y;
            if (aff) {
                fa0 = fmaxf(fa0 * sc0 + sh0, 0.f); fa1 = fmaxf(fa1 * sc1v + sh1v, 0.f);
                fb0 = fmaxf(fb0 * sc0 + sh0, 0.f); fb1 = fmaxf(fb1 * sc1v + sh1v, 0.f);
            }
            const float* epa = eas + (long)e * EAP;
            const float* epb = epa + EAP;
            f32x4 a0v = *(const f32x4*)epa, a1v = *(const f32x4*)(epa + 4), a2v = *(const f32x4*)(epa + 8);
            f32x4 b0v = *(const f32x4*)epb, b1v = *(const f32x4*)(epb + 4), b2v = *(const f32x4*)(epb + 8);
            float eva[12] = {a0v.x, a0v.y, a0v.z, a0v.w, a1v.x, a1v.y, a1v.z, a1v.w, a2v.x, a2v.y, a2v.z, a2v.w};
            float evb[12] = {b0v.x, b0v.y, b0v.z, b0v.w, b1v.x, b1v.y, b1v.z, b1v.w, b2v.x, b2v.y, b2v.z, b2v.w};
            float ca0 = bbv.x, ca1 = bbv.y, cb0 = bbv.x, cb1 = bbv.y;
            #pragma unroll
            for (int k = 0; k < BOND_DIM; ++k) {
                ca0 = fmaf(eva[k], wk0[k], ca0);
                ca1 = fmaf(eva[k], wk1[k], ca1);
                cb0 = fmaf(evb[k], wk0[k], cb0);
                cb1 = fmaf(evb[k], wk1[k], cb1);
            }
            a0 += fmaxf(fa0 + ca0, 0.f);
            a1 += fmaxf(fa1 + ca1, 0.f);
            a0 += fmaxf(fb0 + cb0, 0.f);
            a1 += fmaxf(fb1 + cb1, 0.f);
        }
        if (e < e1) {
            int sv = src_sorted[e];
            f32x2 hv = *(const f32x2*)(h + (long)sv * DD + d0);
            float f0 = hv.x, f1 = hv.y;
            if (aff) {
                f0 = fmaxf(f0 * sc0 + sh0, 0.f); f1 = fmaxf(f1 * sc1v + sh1v, 0.f);
            }
            const float* ep = eas + (long)e * EAP;
            f32x4 ev0 = *(const f32x4*)ep, ev1 = *(const f32x4*)(ep + 4), ev2 = *(const f32x4*)(ep + 8);
            float ev[12] = {ev0.x, ev0.y, ev0.z, ev0.w, ev1.x, ev1.y, ev1.z, ev1.w, ev2.x, ev2.y, ev2.z, ev2.w};
            float c0 = bbv.x, c1 = bbv.y;
            #pragma unroll
            for (int k = 0; k < BOND_DIM; ++k) {
                c0 = fmaf(ev[k], wk0[k], c0);
                c1 = fmaf(ev[k], wk1[k], c1);
            }
            a0 += fmaxf(f0 + c0, 0.f);
            a1 += fmaxf(f1 + c1, 0.f);
        }
        f32x2 tn = *(const f32x2*)(h + (long)n * DD + d0);
        float t0 = tn.x, t1 = tn.y;
        if (aff) {
            t0 = fmaxf(t0 * sc0 + sh0, 0.f); t1 = fmaxf(t1 * sc1v + sh1v, 0.f);
        }
        unsigned pk = (unsigned)f2b(t0 + a0) | ((unsigned)f2b(t1 + a1) << 16);
        *(unsigned*)(sout + (long)n * DD + d0) = pk;
    }
}

// ---------------- weight pre-pack: W[K][N] f32 -> Wf[ks][f][lane][8] bf16 ----
__global__ void pack_w(const float* __restrict__ W, unsigned short* __restrict__ Wf,
                       int Kact, int N, int KSTEPS) {
    int idx = blockIdx.x * blockDim.x + threadIdx.x;
    int NF = N >> 4;
    int total = KSTEPS * NF * 64;
    if (idx >= total) return;
    int l = idx & 63;
    int f = (idx >> 6) % NF;
    int ks = idx / (64 * NF);
    int col = f * 16 + (l & 15);
    int k0 = ks * 32 + (l >> 4) * 8;
    bf16x8 v;
    #pragma unroll
    for (int j = 0; j < 8; ++j) {
        int k = k0 + j;
        v[j] = (k < Kact) ? (short)f2b(W[(long)k * N + col]) : (short)0;
    }
    *(bf16x8*)(Wf + (long)idx * 8) = v;
}

// ---------------- x f32 [N,101] -> xb bf16 [N,128] zero-padded ----------------
__global__ void pack_x(const float* __restrict__ x, unsigned short* __restrict__ xb) {
    const long total = (long)NN * 128;
    for (long i = (long)blockIdx.x * blockDim.x + threadIdx.x; i < total;
         i += (long)gridDim.x * blockDim.x) {
        int col = (int)(i & 127);
        long row = i >> 7;
        xb[i] = (col < ATOM_DIM) ? f2b(x[row * ATOM_DIM + col]) : (unsigned short)0;
    }
}

// ---------------- register-resident-B MFMA GEMM ----------------
// XCD-paired halves (blocks b and b+8 share mt and an XCD) + LDS store epilogue
// MODE 0: A bf16 plain.  MODE 2: A = bf16(relu(A*sc+sh)) in-register.
template<int NF, int KSTEPS, int NHALVES, int MODE, bool OUT_BF16, bool STATS>
__global__ __launch_bounds__(256, 2) void gemm_reg(
    const unsigned short* __restrict__ A,   // [M][K] bf16
    const float* __restrict__ sc, const float* __restrict__ sh,
    const unsigned short* __restrict__ Wf,  // packed [KSTEPS][NFtot][64][8]
    const float* __restrict__ bias,         // [NFtot*16]
    void* __restrict__ outp,
    float* __restrict__ partial,            // [GEMM_GRID][2*NF*16]
    int M)
{
    constexpr int K = KSTEPS * 32;
    constexpr int NCb = NF * 16;
    constexpr int NFtot = NF * NHALVES;
    constexpr int NCtot = NCb * NHALVES;
    constexpr int ESZ = OUT_BF16 ? 2 : 4;
    constexpr int RSTRIDE = NCb + (OUT_BF16 ? 8 : 4);   // LDS row stride (elems), keeps rows 16B-aligned
    constexpr int ROWBYTES = NCb * ESZ;
    constexpr int CHUNKS = 64 * ROWBYTES / 16;
    constexpr int CPR = ROWBYTES / 16;

    __shared__ __align__(16) char sOut[64 * RSTRIDE * ESZ];
    __shared__ float s_sc[(MODE == 2) ? K : 1];
    __shared__ float s_sh[(MODE == 2) ? K : 1];
    __shared__ float s_ps[STATS ? 2 * NCb : 1];

    const int tid = threadIdx.x;
    const int wave = tid >> 6, l = tid & 63;
    const int kg = (l >> 4) * 8;

    // XCD-pair swizzle: halves of the same tile land on the same XCD (b, b+8)
    int half, mt;
    if (NHALVES == 2) {
        int b = blockIdx.x;
        half = (b >> 3) & 1;
        mt = (b & 7) | ((b >> 4) << 3);
    } else {
        half = 0; mt = blockIdx.x;
    }
    const int col0 = half * NCb;
    const int bstep = gridDim.x / NHALVES;

    if (MODE == 2 || STATS) {
        if (MODE == 2) {
            for (int i = tid; i < K; i += 256) { s_sc[i] = sc[i]; s_sh[i] = sh[i]; }
        }
        if (STATS) {
            for (int i = tid; i < 2 * NCb; i += 256) s_ps[i] = 0.f;
        }
        __syncthreads();
    }

    // B panel resident in registers
    bf16x8 bfr[KSTEPS][NF];
    {
        const bf16x8* wp = (const bf16x8*)Wf;
        #pragma unroll
        for (int ks = 0; ks < KSTEPS; ++ks)
            #pragma unroll
            for (int f = 0; f < NF; ++f)
                bfr[ks][f] = wp[((long)ks * NFtot + half * NF + f) * 64 + l];
    }

    float bb[NF];
    #pragma unroll
    for (int f = 0; f < NF; ++f) bb[f] = bias[col0 + f * 16 + (l & 15)];

    float ssum[NF], ssq[NF];
    #pragma unroll
    for (int f = 0; f < NF; ++f) { ssum[f] = 0.f; ssq[f] = 0.f; }

    const int MT = (M + 63) >> 6;

    bf16x8 ldA[KSTEPS], ldB[KSTEPS];
    {
        int rr = mt * 64 + wave * 16 + (l & 15);
        int rc = rr < M ? rr : M - 1;
        const unsigned short* ap = A + (long)rc * K + kg;
        #pragma unroll
        for (int ks = 0; ks < KSTEPS; ++ks) ldA[ks] = *(const bf16x8*)(ap + ks * 32);
    }

    for (; mt < MT; mt += bstep) {
        const int nxt = mt + bstep;
        if (nxt < MT) {   // prefetch next A tile
            int rr = nxt * 64 + wave * 16 + (l & 15);
            int rc = rr < M ? rr : M - 1;
            const unsigned short* ap = A + (long)rc * K + kg;
            #pragma unroll
            for (int ks = 0; ks < KSTEPS; ++ks) ldB[ks] = *(const bf16x8*)(ap + ks * 32);
        }

        if (MODE == 2) {  // in-register BN + relu + re-round
            #pragma unroll
            for (int ks = 0; ks < KSTEPS; ++ks) {
                f32x4 s0 = *(const f32x4*)&s_sc[ks * 32 + kg];
                f32x4 s1 = *(const f32x4*)&s_sc[ks * 32 + kg + 4];
                f32x4 h0 = *(const f32x4*)&s_sh[ks * 32 + kg];
                f32x4 h1 = *(const f32x4*)&s_sh[ks * 32 + kg + 4];
                float sv[8] = {s0.x, s0.y, s0.z, s0.w, s1.x, s1.y, s1.z, s1.w};
                float hv[8] = {h0.x, h0.y, h0.z, h0.w, h1.x, h1.y, h1.z, h1.w};
                #pragma unroll
                for (int j = 0; j < 8; ++j) {
                    float v = fmaxf(b2f(ldA[ks][j]) * sv[j] + hv[j], 0.f);
                    ldA[ks][j] = (short)f2b(v);
                }
            }
        }

        f32x4 acc[NF];
        #pragma unroll
        for (int f = 0; f < NF; ++f) acc[f] = (f32x4){0.f, 0.f, 0.f, 0.f};
        #pragma unroll
        for (int ks = 0; ks < KSTEPS; ++ks)
            #pragma unroll
            for (int f = 0; f < NF; ++f)
                acc[f] = __builtin_amdgcn_mfma_f32_16x16x32_bf16(ldA[ks], bfr[ks][f], acc[f], 0, 0, 0);

        // stage C tile into LDS (+stats in registers)
        const int rtile = mt * 64;
        #pragma unroll
        for (int f = 0; f < NF; ++f) {
            const int cl = f * 16 + (l & 15);
            #pragma unroll
            for (int j = 0; j < 4; ++j) {
                const int rl = wave * 16 + (l >> 4) * 4 + j;
                float v = acc[f][j] + bb[f];
                if (OUT_BF16) ((unsigned short*)sOut)[rl * RSTRIDE + cl] = f2b(v);
                else          ((float*)sOut)[rl * RSTRIDE + cl] = v;
                if (STATS && rtile + rl < M) { ssum[f] += v; ssq[f] += v * v; }
            }
        }
        __syncthreads();

        // stream LDS tile out as full-line 16B stores
        const int rmax = M - rtile;
        #pragma unroll
        for (int i = 0; i < CHUNKS / 256; ++i) {
            int c = i * 256 + tid;
            int row = c / CPR;
            int off = (c % CPR) * 16;
            if (row < rmax) {
                f32x4 v = *(const f32x4*)(sOut + row * (RSTRIDE * ESZ) + off);
                char* gp = (char*)outp + ((long)(rtile + row) * NCtot + col0) * ESZ + off;
                *(f32x4*)gp = v;
            }
        }
        __syncthreads();

        #pragma unroll
        for (int ks = 0; ks < KSTEPS; ++ks) ldA[ks] = ldB[ks];
    }

    if (STATS) {
        #pragma unroll
        for (int f = 0; f < NF; ++f) {
            float s = ssum[f], q = ssq[f];
            s += __shfl_xor(s, 16); s += __shfl_xor(s, 32);
            q += __shfl_xor(q, 16); q += __shfl_xor(q, 32);
            if (l < 16) {
                atomicAdd(&s_ps[f * 16 + l], s);
                atomicAdd(&s_ps[NCb + f * 16 + l], q);
            }
        }
        __syncthreads();
        float* pb = partial + (long)blockIdx.x * 2 * NCb;
        for (int i = tid; i < 2 * NCb; i += 256) pb[i] = s_ps[i];
    }
}

// ---------------- BN finalize from per-block partials ----------------
__global__ __launch_bounds__(64) void bn_finalize_p(
    const float* __restrict__ partial, int nblk, int ncb, int halves,
    const float* __restrict__ gamma, const float* __restrict__ beta,
    float invN, float* __restrict__ sc, float* __restrict__ sh)
{
    const int c = blockIdx.x;
    const int t = threadIdx.x;
    // block b covered cols [((b>>3)&1)*ncb, +ncb) when halves==2
    float s = 0.f, q = 0.f;
    for (int b = t; b < nblk; b += 64) {
        int half = (halves == 2) ? ((b >> 3) & 1) : 0;
        if (c / ncb != half) continue;
        const float* pb = partial + (long)b * 2 * ncb;
        s += pb[c % ncb];
        q += pb[ncb + c % ncb];
    }
    #pragma unroll
    for (int off = 1; off < 64; off <<= 1) {
        s += __shfl_xor(s, off);
        q += __shfl_xor(q, off);
    }
    if (t == 0) {
        float m = s * invN;
        float v = q * invN - m * m;
        float g = gamma[c] * rsqrtf(v + 1e-5f);
        sc[c] = g;
        sh[c] = beta[c] - m * g;
    }
}

// ---------------- pooling ----------------
__global__ __launch_bounds__(128) void pool_kernel(
    const float* __restrict__ hraw,
    const float* __restrict__ sc, const float* __restrict__ sh,
    const void* __restrict__ batchp, const int* __restrict__ flag,
    int Nn, float* __restrict__ out)
{
    const int g = blockIdx.x;
    const int t = threadIdx.x;
    const int is64 = *flag;
    int lo = 0, hi = Nn;
    while (lo < hi) { int mid = (lo + hi) >> 1; if (getIdx(batchp, mid, is64) < g) lo = mid + 1; else hi = mid; }
    const int s0 = lo;
    hi = Nn;
    while (lo < hi) { int mid = (lo + hi) >> 1; if (getIdx(batchp, mid, is64) < g + 1) lo = mid + 1; else hi = mid; }
    const int s1 = lo;
    float acc = 0.f;
    for (int r = s0; r < s1; ++r) acc += hraw[(long)r * DD + t];
    const int cnt = s1 - s0;
    float v = 0.f;
    if (cnt > 0) v = (acc / (float)cnt) * sc[t] + sh[t];
    out[(long)g * DD + t] = v;
}

// ---------------- launch ----------------
extern "C" void kernel_launch(void* const* d_in, const int* in_sizes, int n_in,
                              void* d_out, int out_size, void* d_ws, size_t ws_size,
                              hipStream_t stream)
{
    const float* x     = (const float*)d_in[0];
    const float* ea    = (const float*)d_in[1];
    const float* embW  = (const float*)d_in[2];
    const float* embB  = (const float*)d_in[3];
    const float* bondW = (const float*)d_in[4];
    const float* bondB = (const float*)d_in[5];
    const float* W1    = (const float*)d_in[6];
    const float* b1    = (const float*)d_in[7];
    const float* g1    = (const float*)d_in[8];
    const float* be1   = (const float*)d_in[9];
    const float* W2    = (const float*)d_in[10];
    const float* b2    = (const float*)d_in[11];
    const float* gout  = (const float*)d_in[12];
    const float* bout  = (const float*)d_in[13];
    const void*  eidx  = d_in[14];
    const void*  batch = d_in[15];
    float* out = (float*)d_out;

    char* w = (char*)d_ws;
    float* h    = (float*)w;                    w += (long)NN * DD * 4;        // 51.2MB
    unsigned short* s   = (unsigned short*)w;   w += (long)NN * DD * 2;        // 25.6MB
    unsigned short* z1  = (unsigned short*)w;   w += (long)NN * 256 * 2;       // 51.2MB
    unsigned short* xb  = z1;   // alias: consumed by emb gemm before z1 written
    float* eas  = (float*)w;                    w += (long)EE * EAP * 4;       // 19.2MB
    int* src_sorted = (int*)w;                  w += (long)EE * 4;             // 1.6MB
    int* row_ptr    = (int*)w;                  w += (long)(NN + 1) * 4;
    int* counts     = (int*)w;                  w += (long)NN * 4;
    int* tmp        = (int*)w;                  w += (long)NN * 4;
    int* bsum       = (int*)w;                  w += 1024 * 4;
    int* bsumx      = (int*)w;                  w += 1024 * 4;
    float* partial  = (float*)w;                w += (long)GEMM_GRID * 512 * 4; // 1MB
    float* sc1  = (float*)w;                    w += 256 * 4;
    float* sh1  = (float*)w;                    w += 256 * 4;
    float* sc2  = (float*)w;                    w += 128 * 4;
    float* sh2  = (float*)w;                    w += 128 * 4;
    unsigned short* embWf = (unsigned short*)w; w += 4 * 8  * 64 * 8 * 2;
    unsigned short* W1f   = (unsigned short*)w; w += 3L * 4 * 16 * 64 * 8 * 2;
    unsigned short* W2f   = (unsigned short*)w; w += 3L * 8 * 8  * 64 * 8 * 2;
    int* flag = (int*)w;

    detect64_kernel<<<1, 1, 0, stream>>>(eidx, 256, flag);

    // pre-pack weights / x
    pack_x<<<4096, 256, 0, stream>>>(x, xb);
    pack_w<<<8, 256, 0, stream>>>(embW, embWf, ATOM_DIM, 128, 4);
    for (int i = 0; i < 3; ++i) {
        pack_w<<<16, 256, 0, stream>>>(W1 + (long)i * 128 * 256, W1f + (long)i * 4 * 16 * 64 * 8, 128, 256, 4);
        pack_w<<<16, 256, 0, stream>>>(W2 + (long)i * 256 * 128, W2f + (long)i * 8 * 8 * 64 * 8, 256, 128, 8);
    }

    // counting sort of edges by dst -> CSR
    const int eblocks = (EE + 255) / 256;
    const int nb = (NN + 255) / 256;
    hipMemsetAsync(counts, 0, (size_t)NN * 4, stream);
    hist_kernel<<<eblocks, 256, 0, stream>>>(eidx, flag, counts);
    scan1_kernel<<<nb, 256, 0, stream>>>(counts, tmp, bsum, NN);
    scan2_kernel<<<1, 512, 0, stream>>>(bsum, bsumx, nb);
    scan3_kernel<<<nb, 256, 0, stream>>>(tmp, bsumx, row_ptr, NN);
    hipMemsetAsync(counts, 0, (size_t)NN * 4, stream);
    scatter_kernel<<<eblocks, 256, 0, stream>>>(eidx, flag, ea, row_ptr, counts, src_sorted, eas);

    // h0 = x @ embW + embB   (f32)
    gemm_reg<8, 4, 1, 0, false, false><<<GEMM_GRID, 256, 0, stream>>>(
        xb, nullptr, nullptr, embWf, embB, h, nullptr, NN);

    const float* scin = nullptr;
    const float* shin = nullptr;

    for (int i = 0; i < 3; ++i) {
        // s = bf16( t + sum relu(t[src] + bond) ),  t = bn_relu(h) applied inline
        msg_csr_kernel<<<4096, 256, 0, stream>>>(
            h, scin, shin, src_sorted, row_ptr, eas,
            bondW + (long)i * BOND_DIM * DD, bondB + (long)i * DD, s);

        // z1 = s @ W1 + b1   (bf16 out, per-block stats)
        gemm_reg<8, 4, 2, 0, true, true><<<GEMM_GRID, 256, 0, stream>>>(
            s, nullptr, nullptr, W1f + (long)i * 4 * 16 * 64 * 8,
            b1 + (long)i * 256, z1, partial, NN);
        bn_finalize_p<<<256, 64, 0, stream>>>(partial, GEMM_GRID, 128, 2,
            g1 + (long)i * 256, be1 + (long)i * 256, 1.f / NN, sc1, sh1);

        // h = relu(bn(z1)) @ W2 + b2   (f32 out, per-block stats)
        gemm_reg<4, 8, 2, 2, false, true><<<GEMM_GRID, 256, 0, stream>>>(
            z1, sc1, sh1, W2f + (long)i * 8 * 8 * 64 * 8,
            b2 + (long)i * DD, h, partial, NN);
        bn_finalize_p<<<128, 64, 0, stream>>>(partial, GEMM_GRID, 64, 2,
            gout + (long)i * DD, bout + (long)i * DD, 1.f / NN, sc2, sh2);

        scin = sc2; shin = sh2;
    }

    pool_kernel<<<GG, DD, 0, stream>>>(h, sc2, sh2, batch, flag, NN, out);
}

// Round 9
// 566.113 us; speedup vs baseline: 1.7878x; 1.0499x over previous
//
#include <hip/hip_runtime.h>
#include <hip/hip_bf16.h>

#define NN 100000
#define EE 400000
#define GG 4096
#define DD 128
#define ATOM_DIM 101
#define BOND_DIM 11
#define EAP 12    // padded bond-feature stride (48B)
#define GEMM_GRID 512

typedef __attribute__((ext_vector_type(8))) short bf16x8;
typedef __attribute__((ext_vector_type(4))) float f32x4;
typedef __attribute__((ext_vector_type(2))) float f32x2;

__device__ __forceinline__ float b2f(short s) {
    unsigned u = ((unsigned)(unsigned short)s) << 16;
    float f; __builtin_memcpy(&f, &u, 4); return f;
}
__device__ __forceinline__ unsigned short f2b(float f) {
    unsigned u; __builtin_memcpy(&u, &f, 4);
    u += 0x7FFFu + ((u >> 16) & 1u);          // RNE
    return (unsigned short)(u >> 16);
}

// ---------------- index dtype detection (int32 vs int64) ----------------
__global__ void detect64_kernel(const void* ei, int npairs, int* flag) {
    const int* p = (const int*)ei;
    int any = 0;
    for (int i = 1; i < 2 * npairs; i += 2) any |= p[i];
    *flag = (any == 0) ? 1 : 0;
}
__device__ __forceinline__ int getIdx(const void* p, long i, int is64) {
    if (is64) return (int)(((const long long*)p)[i]);
    return ((const int*)p)[i];
}

// ---------------- counting sort by dst ----------------
__global__ __launch_bounds__(256) void hist_kernel(
    const void* __restrict__ eidx, const int* __restrict__ flag, int* __restrict__ counts) {
    int e = blockIdx.x * 256 + threadIdx.x;
    if (e >= EE) return;
    int is64 = *flag;
    int dn = getIdx(eidx, (long)EE + e, is64);
    atomicAdd(&counts[dn], 1);
}

__global__ __launch_bounds__(256) void scan1_kernel(
    const int* __restrict__ counts, int* __restrict__ tmp, int* __restrict__ bsum, int n) {
    __shared__ int sd[256];
    const int tid = threadIdx.x;
    int i = blockIdx.x * 256 + tid;
    int v = (i < n) ? counts[i] : 0;
    sd[tid] = v; __syncthreads();
    #pragma unroll
    for (int off = 1; off < 256; off <<= 1) {
        int a = (tid >= off) ? sd[tid - off] : 0;
        __syncthreads();
        sd[tid] += a;
        __syncthreads();
    }
    if (i < n) tmp[i] = sd[tid] - v;
    if (tid == 255) bsum[blockIdx.x] = sd[255];
}

__global__ __launch_bounds__(512) void scan2_kernel(
    const int* __restrict__ bsum, int* __restrict__ bsumx, int nb) {
    __shared__ int sd[512];
    const int tid = threadIdx.x;
    int v = (tid < nb) ? bsum[tid] : 0;
    sd[tid] = v; __syncthreads();
    #pragma unroll
    for (int off = 1; off < 512; off <<= 1) {
        int a = (tid >= off) ? sd[tid - off] : 0;
        __syncthreads();
        sd[tid] += a;
        __syncthreads();
    }
    if (tid < nb) bsumx[tid] = sd[tid] - v;
}

__global__ __launch_bounds__(256) void scan3_kernel(
    const int* __restrict__ tmp, const int* __restrict__ bsumx,
    int* __restrict__ row_ptr, int n) {
    int i = blockIdx.x * 256 + threadIdx.x;
    if (i < n) row_ptr[i] = tmp[i] + bsumx[blockIdx.x];
    if (i == 0) row_ptr[n] = EE;
}

__global__ __launch_bounds__(256) void scatter_kernel(
    const void* __restrict__ eidx, const int* __restrict__ flag,
    const float* __restrict__ ea, const int* __restrict__ row_ptr,
    int* __restrict__ cursor, int* __restrict__ src_sorted, float* __restrict__ eas) {
    int e = blockIdx.x * 256 + threadIdx.x;
    if (e >= EE) return;
    int is64 = *flag;
    int dn = getIdx(eidx, (long)EE + e, is64);
    int sv = getIdx(eidx, e, is64);
    int pos = row_ptr[dn] + atomicAdd(&cursor[dn], 1);
    src_sorted[pos] = sv;
    const float* sp = ea + (long)e * BOND_DIM;
    float* dp = eas + (long)pos * EAP;
    #pragma unroll
    for (int k = 0; k < BOND_DIM; ++k) dp[k] = sp[k];
    dp[11] = 0.f;
}

// ---------------- fused transform + message + aggregate (CSR) ----------------
// t(v) = sc? relu(h[v]*sc+sh) : h[v]          (h stored bf16)
// s[n] = bf16( t(n) + sum_{e in N(n)} relu(t(src) + ea[e] @ bw + bb) )
__global__ __launch_bounds__(256) void msg_csr_kernel(
    const unsigned short* __restrict__ h,    // [N][128] bf16
    const float* __restrict__ sc, const float* __restrict__ sh,
    const int* __restrict__ src_sorted, const int* __restrict__ row_ptr,
    const float* __restrict__ eas,
    const float* __restrict__ bw,   // [11][128]
    const float* __restrict__ bb,   // [128]
    unsigned short* __restrict__ sout)
{
    const int tid = threadIdx.x;
    const int wave = tid >> 6, lane = tid & 63;
    const int d0 = lane * 2;
    float wk0[BOND_DIM], wk1[BOND_DIM];
    #pragma unroll
    for (int k = 0; k < BOND_DIM; ++k) {
        f32x2 wv = *(const f32x2*)(bw + k * DD + d0);
        wk0[k] = wv.x; wk1[k] = wv.y;
    }
    f32x2 bbv = *(const f32x2*)(bb + d0);
    const bool aff = (sc != nullptr);
    float sc0 = 1.f, sc1v = 1.f, sh0 = 0.f, sh1v = 0.f;
    if (aff) { sc0 = sc[d0]; sc1v = sc[d0 + 1]; sh0 = sh[d0]; sh1v = sh[d0 + 1]; }

    for (int n = blockIdx.x * 4 + wave; n < NN; n += gridDim.x * 4) {
        const int e0 = row_ptr[n], e1 = row_ptr[n + 1];
        float a0 = 0.f, a1 = 0.f;
        int e = e0;
        for (; e + 2 <= e1; e += 2) {
            int sv0 = src_sorted[e];
            int sv1 = src_sorted[e + 1];
            unsigned tva = *(const unsigned*)(h + (long)sv0 * DD + d0);
            unsigned tvb = *(const unsigned*)(h + (long)sv1 * DD + d0);
            float fa0 = b2f((short)(tva & 0xffff)), fa1 = b2f((short)(tva >> 16));
            float fb0 = b2f((short)(tvb & 0xffff)), fb1 = b2f((short)(tvb >> 16));
            if (aff) {
                fa0 = fmaxf(fa0 * sc0 + sh0, 0.f); fa1 = fmaxf(fa1 * sc1v + sh1v, 0.f);
                fb0 = fmaxf(fb0 * sc0 + sh0, 0.f); fb1 = fmaxf(fb1 * sc1v + sh1v, 0.f);
            }
            const float* epa = eas + (long)e * EAP;
            const float* epb = epa + EAP;
            f32x4 a0v = *(const f32x4*)epa, a1v = *(const f32x4*)(epa + 4), a2v = *(const f32x4*)(epa + 8);
            f32x4 b0v = *(const f32x4*)epb, b1v = *(const f32x4*)(epb + 4), b2v = *(const f32x4*)(epb + 8);
            float eva[12] = {a0v.x, a0v.y, a0v.z, a0v.w, a1v.x, a1v.y, a1v.z, a1v.w, a2v.x, a2v.y, a2v.z, a2v.w};
            float evb[12] = {b0v.x, b0v.y, b0v.z, b0v.w, b1v.x, b1v.y, b1v.z, b1v.w, b2v.x, b2v.y, b2v.z, b2v.w};
            float ca0 = bbv.x, ca1 = bbv.y, cb0 = bbv.x, cb1 = bbv.y;
            #pragma unroll
            for (int k = 0; k < BOND_DIM; ++k) {
                ca0 = fmaf(eva[k], wk0[k], ca0);
                ca1 = fmaf(eva[k], wk1[k], ca1);
                cb0 = fmaf(evb[k], wk0[k], cb0);
                cb1 = fmaf(evb[k], wk1[k], cb1);
            }
            a0 += fmaxf(fa0 + ca0, 0.f);
            a1 += fmaxf(fa1 + ca1, 0.f);
            a0 += fmaxf(fb0 + cb0, 0.f);
            a1 += fmaxf(fb1 + cb1, 0.f);
        }
        if (e < e1) {
            int sv = src_sorted[e];
            unsigned tv = *(const unsigned*)(h + (long)sv * DD + d0);
            float f0 = b2f((short)(tv & 0xffff)), f1 = b2f((short)(tv >> 16));
            if (aff) {
                f0 = fmaxf(f0 * sc0 + sh0, 0.f); f1 = fmaxf(f1 * sc1v + sh1v, 0.f);
            }
            const float* ep = eas + (long)e * EAP;
            f32x4 ev0 = *(const f32x4*)ep, ev1 = *(const f32x4*)(ep + 4), ev2 = *(const f32x4*)(ep + 8);
            float ev[12] = {ev0.x, ev0.y, ev0.z, ev0.w, ev1.x, ev1.y, ev1.z, ev1.w, ev2.x, ev2.y, ev2.z, ev2.w};
            float c0 = bbv.x, c1 = bbv.y;
            #pragma unroll
            for (int k = 0; k < BOND_DIM; ++k) {
                c0 = fmaf(ev[k], wk0[k], c0);
                c1 = fmaf(ev[k], wk1[k], c1);
            }
            a0 += fmaxf(f0 + c0, 0.f);
            a1 += fmaxf(f1 + c1, 0.f);
        }
        unsigned tn = *(const unsigned*)(h + (long)n * DD + d0);
        float t0 = b2f((short)(tn & 0xffff)), t1 = b2f((short)(tn >> 16));
        if (aff) {
            t0 = fmaxf(t0 * sc0 + sh0, 0.f); t1 = fmaxf(t1 * sc1v + sh1v, 0.f);
        }
        unsigned pk = (unsigned)f2b(t0 + a0) | ((unsigned)f2b(t1 + a1) << 16);
        *(unsigned*)(sout + (long)n * DD + d0) = pk;
    }
}

// ---------------- weight pre-pack: W[K][N] f32 -> Wf[ks][f][lane][8] bf16 ----
__global__ void pack_w(const float* __restrict__ W, unsigned short* __restrict__ Wf,
                       int Kact, int N, int KSTEPS) {
    int idx = blockIdx.x * blockDim.x + threadIdx.x;
    int NF = N >> 4;
    int total = KSTEPS * NF * 64;
    if (idx >= total) return;
    int l = idx & 63;
    int f = (idx >> 6) % NF;
    int ks = idx / (64 * NF);
    int col = f * 16 + (l & 15);
    int k0 = ks * 32 + (l >> 4) * 8;
    bf16x8 v;
    #pragma unroll
    for (int j = 0; j < 8; ++j) {
        int k = k0 + j;
        v[j] = (k < Kact) ? (short)f2b(W[(long)k * N + col]) : (short)0;
    }
    *(bf16x8*)(Wf + (long)idx * 8) = v;
}

// ---------------- x f32 [N,101] -> xb bf16 [N,128] zero-padded ----------------
__global__ void pack_x(const float* __restrict__ x, unsigned short* __restrict__ xb) {
    const long total = (long)NN * 128;
    for (long i = (long)blockIdx.x * blockDim.x + threadIdx.x; i < total;
         i += (long)gridDim.x * blockDim.x) {
        int col = (int)(i & 127);
        long row = i >> 7;
        xb[i] = (col < ATOM_DIM) ? f2b(x[row * ATOM_DIM + col]) : (unsigned short)0;
    }
}

// ---------------- register-resident-B MFMA GEMM ----------------
// XCD-paired halves (blocks b and b+8 share mt and an XCD) + LDS store epilogue
// MODE 0: A bf16 plain.  MODE 2: A = bf16(relu(A*sc+sh)) in-register.
template<int NF, int KSTEPS, int NHALVES, int MODE, bool OUT_BF16, bool STATS>
__global__ __launch_bounds__(256, 2) void gemm_reg(
    const unsigned short* __restrict__ A,   // [M][K] bf16
    const float* __restrict__ sc, const float* __restrict__ sh,
    const unsigned short* __restrict__ Wf,  // packed [KSTEPS][NFtot][64][8]
    const float* __restrict__ bias,         // [NFtot*16]
    void* __restrict__ outp,
    float* __restrict__ partial,            // [GEMM_GRID][2*NF*16]
    int M)
{
    constexpr int K = KSTEPS * 32;
    constexpr int NCb = NF * 16;
    constexpr int NFtot = NF * NHALVES;
    constexpr int NCtot = NCb * NHALVES;
    constexpr int ESZ = OUT_BF16 ? 2 : 4;
    constexpr int RSTRIDE = NCb + (OUT_BF16 ? 8 : 4);   // LDS row stride (elems)
    constexpr int ROWBYTES = NCb * ESZ;
    constexpr int CHUNKS = 64 * ROWBYTES / 16;
    constexpr int CPR = ROWBYTES / 16;

    __shared__ __align__(16) char sOut[64 * RSTRIDE * ESZ];
    __shared__ float s_sc[(MODE == 2) ? K : 1];
    __shared__ float s_sh[(MODE == 2) ? K : 1];
    __shared__ float s_ps[STATS ? 2 * NCb : 1];

    const int tid = threadIdx.x;
    const int wave = tid >> 6, l = tid & 63;
    const int kg = (l >> 4) * 8;

    // XCD-pair swizzle: halves of the same tile land on the same XCD (b, b+8)
    int half, mt;
    if (NHALVES == 2) {
        int b = blockIdx.x;
        half = (b >> 3) & 1;
        mt = (b & 7) | ((b >> 4) << 3);
    } else {
        half = 0; mt = blockIdx.x;
    }
    const int col0 = half * NCb;
    const int bstep = gridDim.x / NHALVES;

    if (MODE == 2 || STATS) {
        if (MODE == 2) {
            for (int i = tid; i < K; i += 256) { s_sc[i] = sc[i]; s_sh[i] = sh[i]; }
        }
        if (STATS) {
            for (int i = tid; i < 2 * NCb; i += 256) s_ps[i] = 0.f;
        }
        __syncthreads();
    }

    // B panel resident in registers
    bf16x8 bfr[KSTEPS][NF];
    {
        const bf16x8* wp = (const bf16x8*)Wf;
        #pragma unroll
        for (int ks = 0; ks < KSTEPS; ++ks)
            #pragma unroll
            for (int f = 0; f < NF; ++f)
                bfr[ks][f] = wp[((long)ks * NFtot + half * NF + f) * 64 + l];
    }

    float bb[NF];
    #pragma unroll
    for (int f = 0; f < NF; ++f) bb[f] = bias[col0 + f * 16 + (l & 15)];

    float ssum[NF], ssq[NF];
    #pragma unroll
    for (int f = 0; f < NF; ++f) { ssum[f] = 0.f; ssq[f] = 0.f; }

    const int MT = (M + 63) >> 6;

    bf16x8 ldA[KSTEPS], ldB[KSTEPS];
    {
        int rr = mt * 64 + wave * 16 + (l & 15);
        int rc = rr < M ? rr : M - 1;
        const unsigned short* ap = A + (long)rc * K + kg;
        #pragma unroll
        for (int ks = 0; ks < KSTEPS; ++ks) ldA[ks] = *(const bf16x8*)(ap + ks * 32);
    }

    for (; mt < MT; mt += bstep) {
        const int nxt = mt + bstep;
        if (nxt < MT) {   // prefetch next A tile
            int rr = nxt * 64 + wave * 16 + (l & 15);
            int rc = rr < M ? rr : M - 1;
            const unsigned short* ap = A + (long)rc * K + kg;
            #pragma unroll
            for (int ks = 0; ks < KSTEPS; ++ks) ldB[ks] = *(const bf16x8*)(ap + ks * 32);
        }

        if (MODE == 2) {  // in-register BN + relu + re-round
            #pragma unroll
            for (int ks = 0; ks < KSTEPS; ++ks) {
                f32x4 s0 = *(const f32x4*)&s_sc[ks * 32 + kg];
                f32x4 s1 = *(const f32x4*)&s_sc[ks * 32 + kg + 4];
                f32x4 h0 = *(const f32x4*)&s_sh[ks * 32 + kg];
                f32x4 h1 = *(const f32x4*)&s_sh[ks * 32 + kg + 4];
                float sv[8] = {s0.x, s0.y, s0.z, s0.w, s1.x, s1.y, s1.z, s1.w};
                float hv[8] = {h0.x, h0.y, h0.z, h0.w, h1.x, h1.y, h1.z, h1.w};
                #pragma unroll
                for (int j = 0; j < 8; ++j) {
                    float v = fmaxf(b2f(ldA[ks][j]) * sv[j] + hv[j], 0.f);
                    ldA[ks][j] = (short)f2b(v);
                }
            }
        }

        f32x4 acc[NF];
        #pragma unroll
        for (int f = 0; f < NF; ++f) acc[f] = (f32x4){0.f, 0.f, 0.f, 0.f};
        #pragma unroll
        for (int ks = 0; ks < KSTEPS; ++ks)
            #pragma unroll
            for (int f = 0; f < NF; ++f)
                acc[f] = __builtin_amdgcn_mfma_f32_16x16x32_bf16(ldA[ks], bfr[ks][f], acc[f], 0, 0, 0);

        // stage C tile into LDS (+stats in registers, on f32 pre-round values)
        const int rtile = mt * 64;
        #pragma unroll
        for (int f = 0; f < NF; ++f) {
            const int cl = f * 16 + (l & 15);
            #pragma unroll
            for (int j = 0; j < 4; ++j) {
                const int rl = wave * 16 + (l >> 4) * 4 + j;
                float v = acc[f][j] + bb[f];
                if (OUT_BF16) ((unsigned short*)sOut)[rl * RSTRIDE + cl] = f2b(v);
                else          ((float*)sOut)[rl * RSTRIDE + cl] = v;
                if (STATS && rtile + rl < M) { ssum[f] += v; ssq[f] += v * v; }
            }
        }
        __syncthreads();

        // stream LDS tile out as full-line 16B stores
        const int rmax = M - rtile;
        #pragma unroll
        for (int i = 0; i < CHUNKS / 256; ++i) {
            int c = i * 256 + tid;
            int row = c / CPR;
            int off = (c % CPR) * 16;
            if (row < rmax) {
                f32x4 v = *(const f32x4*)(sOut + row * (RSTRIDE * ESZ) + off);
                char* gp = (char*)outp + ((long)(rtile + row) * NCtot + col0) * ESZ + off;
                *(f32x4*)gp = v;
            }
        }
        __syncthreads();

        #pragma unroll
        for (int ks = 0; ks < KSTEPS; ++ks) ldA[ks] = ldB[ks];
    }

    if (STATS) {
        #pragma unroll
        for (int f = 0; f < NF; ++f) {
            float s = ssum[f], q = ssq[f];
            s += __shfl_xor(s, 16); s += __shfl_xor(s, 32);
            q += __shfl_xor(q, 16); q += __shfl_xor(q, 32);
            if (l < 16) {
                atomicAdd(&s_ps[f * 16 + l], s);
                atomicAdd(&s_ps[NCb + f * 16 + l], q);
            }
        }
        __syncthreads();
        float* pb = partial + (long)blockIdx.x * 2 * NCb;
        for (int i = tid; i < 2 * NCb; i += 256) pb[i] = s_ps[i];
    }
}

// ---------------- BN finalize from per-block partials ----------------
__global__ __launch_bounds__(64) void bn_finalize_p(
    const float* __restrict__ partial, int nblk, int ncb, int halves,
    const float* __restrict__ gamma, const float* __restrict__ beta,
    float invN, float* __restrict__ sc, float* __restrict__ sh)
{
    const int c = blockIdx.x;
    const int t = threadIdx.x;
    float s = 0.f, q = 0.f;
    for (int b = t; b < nblk; b += 64) {
        int half = (halves == 2) ? ((b >> 3) & 1) : 0;
        if (c / ncb != half) continue;
        const float* pb = partial + (long)b * 2 * ncb;
        s += pb[c % ncb];
        q += pb[ncb + c % ncb];
    }
    #pragma unroll
    for (int off = 1; off < 64; off <<= 1) {
        s += __shfl_xor(s, off);
        q += __shfl_xor(q, off);
    }
    if (t == 0) {
        float m = s * invN;
        float v = q * invN - m * m;
        float g = gamma[c] * rsqrtf(v + 1e-5f);
        sc[c] = g;
        sh[c] = beta[c] - m * g;
    }
}

// ---------------- pooling (bf16 h) ----------------
__global__ __launch_bounds__(128) void pool_kernel(
    const unsigned short* __restrict__ h,
    const float* __restrict__ sc, const float* __restrict__ sh,
    const void* __restrict__ batchp, const int* __restrict__ flag,
    int Nn, float* __restrict__ out)
{
    const int g = blockIdx.x;
    const int t = threadIdx.x;
    const int is64 = *flag;
    int lo = 0, hi = Nn;
    while (lo < hi) { int mid = (lo + hi) >> 1; if (getIdx(batchp, mid, is64) < g) lo = mid + 1; else hi = mid; }
    const int s0 = lo;
    hi = Nn;
    while (lo < hi) { int mid = (lo + hi) >> 1; if (getIdx(batchp, mid, is64) < g + 1) lo = mid + 1; else hi = mid; }
    const int s1 = lo;
    float acc = 0.f;
    for (int r = s0; r < s1; ++r) acc += b2f((short)h[(long)r * DD + t]);
    const int cnt = s1 - s0;
    float v = 0.f;
    if (cnt > 0) v = (acc / (float)cnt) * sc[t] + sh[t];
    out[(long)g * DD + t] = v;
}

// ---------------- launch ----------------
extern "C" void kernel_launch(void* const* d_in, const int* in_sizes, int n_in,
                              void* d_out, int out_size, void* d_ws, size_t ws_size,
                              hipStream_t stream)
{
    const float* x     = (const float*)d_in[0];
    const float* ea    = (const float*)d_in[1];
    const float* embW  = (const float*)d_in[2];
    const float* embB  = (const float*)d_in[3];
    const float* bondW = (const float*)d_in[4];
    const float* bondB = (const float*)d_in[5];
    const float* W1    = (const float*)d_in[6];
    const float* b1    = (const float*)d_in[7];
    const float* g1    = (const float*)d_in[8];
    const float* be1   = (const float*)d_in[9];
    const float* W2    = (const float*)d_in[10];
    const float* b2    = (const float*)d_in[11];
    const float* gout  = (const float*)d_in[12];
    const float* bout  = (const float*)d_in[13];
    const void*  eidx  = d_in[14];
    const void*  batch = d_in[15];
    float* out = (float*)d_out;

    char* w = (char*)d_ws;
    unsigned short* h   = (unsigned short*)w;   w += (long)NN * DD * 2;        // 25.6MB
    unsigned short* s   = (unsigned short*)w;   w += (long)NN * DD * 2;        // 25.6MB
    unsigned short* z1  = (unsigned short*)w;   w += (long)NN * 256 * 2;       // 51.2MB
    unsigned short* xb  = z1;   // alias: consumed by emb gemm before z1 written
    float* eas  = (float*)w;                    w += (long)EE * EAP * 4;       // 19.2MB
    int* src_sorted = (int*)w;                  w += (long)EE * 4;             // 1.6MB
    int* row_ptr    = (int*)w;                  w += (long)(NN + 1) * 4;
    int* counts     = (int*)w;                  w += (long)NN * 4;
    int* tmp        = (int*)w;                  w += (long)NN * 4;
    int* bsum       = (int*)w;                  w += 1024 * 4;
    int* bsumx      = (int*)w;                  w += 1024 * 4;
    float* partial  = (float*)w;                w += (long)GEMM_GRID * 512 * 4; // 1MB
    float* sc1  = (float*)w;                    w += 256 * 4;
    float* sh1  = (float*)w;                    w += 256 * 4;
    float* sc2  = (float*)w;                    w += 128 * 4;
    float* sh2  = (float*)w;                    w += 128 * 4;
    unsigned short* embWf = (unsigned short*)w; w += 4 * 8  * 64 * 8 * 2;
    unsigned short* W1f   = (unsigned short*)w; w += 3L * 4 * 16 * 64 * 8 * 2;
    unsigned short* W2f   = (unsigned short*)w; w += 3L * 8 * 8  * 64 * 8 * 2;
    int* flag = (int*)w;

    detect64_kernel<<<1, 1, 0, stream>>>(eidx, 256, flag);

    // pre-pack weights / x
    pack_x<<<4096, 256, 0, stream>>>(x, xb);
    pack_w<<<8, 256, 0, stream>>>(embW, embWf, ATOM_DIM, 128, 4);
    for (int i = 0; i < 3; ++i) {
        pack_w<<<16, 256, 0, stream>>>(W1 + (long)i * 128 * 256, W1f + (long)i * 4 * 16 * 64 * 8, 128, 256, 4);
        pack_w<<<16, 256, 0, stream>>>(W2 + (long)i * 256 * 128, W2f + (long)i * 8 * 8 * 64 * 8, 256, 128, 8);
    }

    // counting sort of edges by dst -> CSR
    const int eblocks = (EE + 255) / 256;
    const int nb = (NN + 255) / 256;
    hipMemsetAsync(counts, 0, (size_t)NN * 4, stream);
    hist_kernel<<<eblocks, 256, 0, stream>>>(eidx, flag, counts);
    scan1_kernel<<<nb, 256, 0, stream>>>(counts, tmp, bsum, NN);
    scan2_kernel<<<1, 512, 0, stream>>>(bsum, bsumx, nb);
    scan3_kernel<<<nb, 256, 0, stream>>>(tmp, bsumx, row_ptr, NN);
    hipMemsetAsync(counts, 0, (size_t)NN * 4, stream);
    scatter_kernel<<<eblocks, 256, 0, stream>>>(eidx, flag, ea, row_ptr, counts, src_sorted, eas);

    // h0 = bf16(x @ embW + embB)
    gemm_reg<8, 4, 1, 0, true, false><<<GEMM_GRID, 256, 0, stream>>>(
        xb, nullptr, nullptr, embWf, embB, h, nullptr, NN);

    const float* scin = nullptr;
    const float* shin = nullptr;

    for (int i = 0; i < 3; ++i) {
        // s = bf16( t + sum relu(t[src] + bond) ),  t = bn_relu(h) applied inline
        msg_csr_kernel<<<4096, 256, 0, stream>>>(
            h, scin, shin, src_sorted, row_ptr, eas,
            bondW + (long)i * BOND_DIM * DD, bondB + (long)i * DD, s);

        // z1 = s @ W1 + b1   (bf16 out, per-block stats)
        gemm_reg<8, 4, 2, 0, true, true><<<GEMM_GRID, 256, 0, stream>>>(
            s, nullptr, nullptr, W1f + (long)i * 4 * 16 * 64 * 8,
            b1 + (long)i * 256, z1, partial, NN);
        bn_finalize_p<<<256, 64, 0, stream>>>(partial, GEMM_GRID, 128, 2,
            g1 + (long)i * 256, be1 + (long)i * 256, 1.f / NN, sc1, sh1);

        // h = bf16(relu(bn(z1)) @ W2 + b2)   (stats on f32 pre-round)
        gemm_reg<4, 8, 2, 2, true, true><<<GEMM_GRID, 256, 0, stream>>>(
            z1, sc1, sh1, W2f + (long)i * 8 * 8 * 64 * 8,
            b2 + (long)i * DD, h, partial, NN);
        bn_finalize_p<<<128, 64, 0, stream>>>(partial, GEMM_GRID, 64, 2,
            gout + (long)i * DD, bout + (long)i * DD, 1.f / NN, sc2, sh2);

        scin = sc2; shin = sh2;
    }

    pool_kernel<<<GG, DD, 0, stream>>>(h, sc2, sh2, batch, flag, NN, out);
}